// Round 6
// baseline (952.705 us; speedup 1.0000x reference)
//
#include <hip/hip_runtime.h>
#include <math.h>

#define PI_F      3.14159265358979323846f
#define TWOPI_F   6.28318530717958647692f
#define HALFPI_F  1.57079632679489661923f
#define ANG_F     0.8944271909999159f

// ---- staging layout (doubles) ----
#define SG_PIX   0      // RAW: sum x, x^2, x^3, x^4
#define SG_MAG   4      // 18 magnitude sums
#define SG_HISQ  22     // sum hi^2
#define SG_PMAG  23     // 12 parent-mag sums (s=0..2, b=0..3)
#define SG_IMM   35     // 5 x (sum im^2, im^3, im^4)
#define SG_ACP   50     // [4 partitions][21 planes][81] raw ac sums (planes: 0..15 = ACE(s,b), 16..20 = ACR(s))
#define SG_C0    6854   // [4][16]     raw
#define SG_CR    6918   // [4][16]
#define SG_CX    6982   // [3][16]     raw
#define SG_CRX   7030   // [4][4*8]
#define SG_CR5   7158   // [25]
#define NSTG     7183

enum { MA_C2 = 0, MA_REAL, MA_BAND, MA_EMBED_BAND, MA_EMBED_LO, MA_IMF4, MA_IM };
enum { WB_WRITE = 0, WB_WRITE_MAG, WB_WRITE_IM, WB_RED_HI, WB_RED_ABSRE, WB_FWD_MASK, WB_PDOTS };

__device__ __forceinline__ int sfreq(int k, int H) { return (k < (H >> 1)) ? k : k - H; }
__device__ __forceinline__ int skx(int i) { return i + (i >> 4); }   // LDS bank skew

__device__ __forceinline__ float d_lograd(int fy, int fx, int H) {
  float cy = (float)fy * (2.0f / (float)H);
  float cx = (float)fx * (2.0f / (float)H);
  float rad = sqrtf(cx * cx + cy * cy);
  if (fy == 0 && fx == 0) rad = 2.0f / (float)H;   // reference DC hack
  return log2f(rad);
}
__device__ __forceinline__ float d_angle(int fy, int fx, int H) {
  return atan2f((float)fy * (2.0f / (float)H), (float)fx * (2.0f / (float)H));
}
__device__ __forceinline__ float d_rc(float x) {
  float c = fminf(fmaxf(-x, 0.0f), 1.0f);
  float t = cosf(0.5f * PI_F * c);
  return t * t;
}
__device__ __forceinline__ float d_alfa(float ang, int b) {
  float bc = (b == 0) ? 0.0f : (b == 1) ? 0.78539816339744830962f
           : (b == 2) ? 1.57079632679489661923f : 2.35619449019234492885f;
  float t = (PI_F + ang) - bc;
  float m = fmodf(t, TWOPI_F);
  if (m < 0.0f) m += TWOPI_F;
  return m - PI_F;
}
__device__ __forceinline__ float d_cos3(float a) { float c = cosf(a); return ANG_F * c * c * c; }
__device__ __forceinline__ float d_amaskC(float ang, int b) {
  float alfa = d_alfa(ang, b);
  float A = d_cos3(alfa);
  return (fabsf(alfa) < HALFPI_F) ? 2.0f * A : 0.0f;
}
__device__ __forceinline__ float d_lo(int fy, int fx, int H) {
  return sqrtf(fmaxf(1.0f - d_rc(d_lograd(fy, fx, H)), 0.0f));
}
// recon mask at native size H
__device__ __forceinline__ float d_mm(int fy, int fx, int H) {
  float lr = d_lograd(fy, fx, H);
  float hm2 = d_rc(lr + 1.0f);
  float lo0 = sqrtf(fmaxf(1.0f - d_rc(lr), 0.0f));
  float ang1 = d_angle(fy, fx, H);
  int gfy = (fy == -(H >> 1)) ? fy : -fy;
  int gfx = (fx == -(H >> 1)) ? fx : -fx;
  float ang2 = d_angle(gfy, gfx, H);
  float msum = 0.0f;
  #pragma unroll
  for (int b4 = 0; b4 < 4; b4++) {
    float a1 = d_alfa(ang1, b4), a2 = d_alfa(ang2, b4);
    float A1 = d_cos3(a1), A2 = d_cos3(a2);
    float T1 = (fabsf(a1) < HALFPI_F) ? A1 : 0.0f;
    float T2 = (fabsf(a2) < HALFPI_F) ? A2 : 0.0f;
    msum += A1 * (T1 - T2);
  }
  return lo0 * hm2 * msum;
}
// accumulated im-chain mask at scale with native size N (N>=128)
template<int N>
__device__ __forceinline__ float d_G(int fy, int fx) {
  float g = d_mm(fy, fx, N);
  float chain = 1.0f;
  #pragma unroll
  for (int Nj = (N >> 1); Nj >= 64; Nj >>= 1) {
    int h = Nj >> 1;
    if (fy < -h || fy >= h || fx < -h || fx >= h) break;
    chain *= d_lo(fy, fx, Nj);
    if (Nj > 64) g += chain * d_mm(fy, fx, Nj);
    else g += chain * d_lo(fy, fx, 64);
  }
  if (fy == 0 && fx == 0) g = 0.0f;
  return g;
}
__device__ __forceinline__ unsigned fkey(float f) {
  unsigned u = __float_as_uint(f);
  return (u & 0x80000000u) ? ~u : (u | 0x80000000u);
}
__device__ __forceinline__ float funkey(unsigned k) {
  return (k & 0x80000000u) ? __uint_as_float(k & 0x7FFFFFFFu) : __uint_as_float(~k);
}

template<int K>
__device__ __forceinline__ void blk_reduce(float* v, float* red) {
  int tid = threadIdx.x, wave = tid >> 6, lane = tid & 63;
  #pragma unroll
  for (int k = 0; k < K; k++) {
    float x = v[k];
    #pragma unroll
    for (int o = 32; o; o >>= 1) x += __shfl_down(x, o, 64);
    if (lane == 0) red[wave * K + k] = x;
  }
  __syncthreads();
  if (tid < K) red[tid] = red[tid] + red[K + tid] + red[2 * K + tid] + red[3 * K + tid];
}

// ================= FFT core (Stockham, radix-4 with leading radix-2) =================
template<int N> struct FftConst {
  static constexpr int L2N = (N == 64) ? 6 : (N == 128) ? 7 : (N == 256) ? 8 : (N == 512) ? 9 : 10;
  static constexpr int TPR = (N / 4 >= 256) ? 256 : ((N / 4 < 16) ? 16 : N / 4);
  static constexpr int RPB = 256 / TPR;
  static constexpr int BUF = N + (N >> 4);
};

template<int N, bool INV>
__device__ __forceinline__ float2* fft_core(float2* A, float2* B, const float2* tw, int tr) {
  constexpr int TPR = FftConst<N>::TPR;
  constexpr int L2N = FftConst<N>::L2N;
  float2* src = A; float2* dst = B;
  if constexpr (L2N & 1) {
    for (int t = tr; t < (N >> 1); t += TPR) {
      float2 w = tw[t];
      float cv = w.x, sv = INV ? w.y : -w.y;
      float2 a = src[skx(t)];
      float2 b = src[skx(t + (N >> 1))];
      float dx = a.x - b.x, dy = a.y - b.y;
      dst[skx(2 * t)] = make_float2(a.x + b.x, a.y + b.y);
      dst[skx(2 * t + 1)] = make_float2(dx * cv - dy * sv, dx * sv + dy * cv);
    }
    __syncthreads();
    float2* tmp = src; src = dst; dst = tmp;
  }
  #pragma unroll
  for (int st = (L2N & 1); st < L2N; st += 2) {
    for (int t = tr; t < (N >> 2); t += TPR) {
      int p = t >> st;
      int q = t & ((1 << st) - 1);
      int i0 = q + (p << st);
      float2 x0 = src[skx(i0)];
      float2 x1 = src[skx(i0 + (N >> 2))];
      float2 x2 = src[skx(i0 + (N >> 1))];
      float2 x3 = src[skx(i0 + 3 * (N >> 2))];
      float2 w = tw[p << st];
      float c1 = w.x, s1 = INV ? w.y : -w.y;
      float c2 = c1 * c1 - s1 * s1, s2 = 2.f * c1 * s1;
      float c3 = c2 * c1 - s2 * s1, s3 = c2 * s1 + s2 * c1;
      float e0x = x0.x + x2.x, e0y = x0.y + x2.y;
      float e1x = x0.x - x2.x, e1y = x0.y - x2.y;
      float o0x = x1.x + x3.x, o0y = x1.y + x3.y;
      float d1x = x1.x - x3.x, d1y = x1.y - x3.y;
      float o1x, o1y;
      if constexpr (INV) { o1x = -d1y; o1y = d1x; }
      else               { o1x = d1y;  o1y = -d1x; }
      float t1x = e1x + o1x, t1y = e1y + o1y;
      float t2x = e0x - o0x, t2y = e0y - o0y;
      float t3x = e1x - o1x, t3y = e1y - o1y;
      int o = q + (p << (st + 2));
      int s = 1 << st;
      dst[skx(o)]         = make_float2(e0x + o0x, e0y + o0y);
      dst[skx(o + s)]     = make_float2(t1x * c1 - t1y * s1, t1x * s1 + t1y * c1);
      dst[skx(o + 2 * s)] = make_float2(t2x * c2 - t2y * s2, t2x * s2 + t2y * c2);
      dst[skx(o + 3 * s)] = make_float2(t3x * c3 - t3y * s3, t3x * s3 + t3y * c3);
    }
    __syncthreads();
    float2* tmp = src; src = dst; dst = tmp;
  }
  return src;
}

struct PAp {
  const float2* in[6];
  float2* out[6];
  const float2* twg;
  int mode[6];
  int aux[6];
};
struct PBp {
  const float2* in[6];
  float2* out[6];
  float2* out2;
  const float2* Bp[4];
  double* red[6];
  double* red2;
  double* cx;
  double* crx;
  const float2* twg;
  int wmode[6];
  int aux[6];
};
struct TPp { const float2* src[6]; float2* dst[6]; };
struct ACp { const float2* in[5]; int pi[5]; int mode[5]; };

template<int N, int MODE>
__device__ __forceinline__ float2 loadA(const float2* in, int row, int i, int b) {
  if constexpr (MODE == MA_C2) {
    return in[(size_t)row * N + i];
  } else if constexpr (MODE == MA_REAL) {
    const float* f = (const float*)in;
    return make_float2(f[(size_t)row * N + i], 0.0f);
  } else if constexpr (MODE == MA_BAND) {
    int fy = sfreq(i, N), fx = sfreq(row, N);
    float m = sqrtf(d_rc(d_lograd(fy, fx, N) + 1.0f)) * d_amaskC(d_angle(fy, fx, N), b);
    float2 l = in[(size_t)row * N + i];
    return make_float2(-l.y * m, l.x * m);
  } else if constexpr (MODE == MA_EMBED_BAND) {
    int fy = sfreq(i, N), fx = sfreq(row, N);
    int q = N >> 2, h2 = N >> 1;
    if (fy < -q || fy >= q || fx < -q || fx >= q) return make_float2(0.f, 0.f);
    int U = fx >= 0 ? fx : fx + h2, V = fy >= 0 ? fy : fy + h2;
    float m = sqrtf(d_rc(d_lograd(fy, fx, h2) + 1.0f)) * d_amaskC(d_angle(fy, fx, h2), b);
    float2 l = in[(size_t)U * h2 + V];
    return make_float2(-l.y * m, l.x * m);
  } else if constexpr (MODE == MA_EMBED_LO) {
    int fy = sfreq(i, N), fx = sfreq(row, N);
    int q = N >> 2, h2 = N >> 1;
    if (fy < -q || fy >= q || fx < -q || fx >= q) return make_float2(0.f, 0.f);
    int U = fx >= 0 ? fx : fx + h2, V = fy >= 0 ? fy : fy + h2;
    return in[(size_t)U * h2 + V];
  } else if constexpr (MODE == MA_IMF4) {
    int fy = sfreq(i, N), fx = sfreq(row, N);
    float lo = d_lo(fy, fx, N);
    float2 v = in[(size_t)row * N + i];
    return make_float2(v.x * lo, v.y * lo);
  } else {  // MA_IM
    int fy = sfreq(i, N), fx = sfreq(row, N);
    float g = d_G<N>(fy, fx);
    float2 l = in[(size_t)row * N + i];
    return make_float2(l.x * g, l.y * g);
  }
}

// pass A: fused load op -> row FFT -> write
template<int N, bool INV>
__global__ __launch_bounds__(256) void k_passA(PAp p) {
  using FC = FftConst<N>;
  __shared__ float2 shA[FC::RPB][FC::BUF];
  __shared__ float2 shB[FC::RPB][FC::BUF];
  __shared__ float2 tw[N / 2];
  int tid = threadIdx.x;
  for (int k = tid; k < N / 2; k += 256) tw[k] = p.twg[k << (10 - FC::L2N)];
  int rl = tid / FC::TPR;
  int tr = tid % FC::TPR;
  int row = blockIdx.x * FC::RPB + rl;
  int plane = blockIdx.y;
  const float2* in = p.in[plane];
  int mode = p.mode[plane];
  int b = p.aux[plane];
  float2* A = shA[rl];
  switch (mode) {
    case MA_C2:         for (int i = tr; i < N; i += FC::TPR) A[skx(i)] = loadA<N, MA_C2>(in, row, i, b); break;
    case MA_REAL:       for (int i = tr; i < N; i += FC::TPR) A[skx(i)] = loadA<N, MA_REAL>(in, row, i, b); break;
    case MA_BAND:       for (int i = tr; i < N; i += FC::TPR) A[skx(i)] = loadA<N, MA_BAND>(in, row, i, b); break;
    case MA_EMBED_BAND: for (int i = tr; i < N; i += FC::TPR) A[skx(i)] = loadA<N, MA_EMBED_BAND>(in, row, i, b); break;
    case MA_EMBED_LO:   for (int i = tr; i < N; i += FC::TPR) A[skx(i)] = loadA<N, MA_EMBED_LO>(in, row, i, b); break;
    case MA_IMF4:       for (int i = tr; i < N; i += FC::TPR) A[skx(i)] = loadA<N, MA_IMF4>(in, row, i, b); break;
    default:            for (int i = tr; i < N; i += FC::TPR) A[skx(i)] = loadA<N, MA_IM>(in, row, i, b); break;
  }
  __syncthreads();
  float2* res = fft_core<N, INV>(A, shB[rl], tw, tr);
  constexpr float sc = INV ? 1.0f / (float)N : 1.0f;
  float2* o = p.out[plane] + (size_t)row * N;
  for (int i = tr; i < N; i += FC::TPR) {
    float2 v = res[skx(i)];
    o[i] = make_float2(v.x * sc, v.y * sc);
  }
}

// forward passA over the raw image with fused raw pixel moments + min/max
__global__ __launch_bounds__(256) void k_fwdA(const float* __restrict__ img, float2* __restrict__ out,
                                              const float2* __restrict__ twg, double* stg, unsigned* stgu) {
  using FC = FftConst<1024>;
  __shared__ float2 shA[FC::BUF];
  __shared__ float2 shB[FC::BUF];
  __shared__ float2 tw[512];
  __shared__ float red[16];
  int tid = threadIdx.x;
  for (int k = tid; k < 512; k += 256) tw[k] = twg[k];
  int row = blockIdx.x;
  float s1 = 0.f, s2 = 0.f, s3 = 0.f, s4 = 0.f;
  float mn = 3.402823466e38f, mx = -3.402823466e38f;
  for (int i = tid; i < 1024; i += 256) {
    float x = img[(size_t)row * 1024 + i];
    shA[skx(i)] = make_float2(x, 0.f);
    float x2 = x * x;
    s1 += x; s2 += x2; s3 += x2 * x; s4 += x2 * x2;
    mn = fminf(mn, x); mx = fmaxf(mx, x);
  }
  float accv[4] = {s1, s2, s3, s4};
  blk_reduce<4>(accv, red);
  if (tid < 4) atomicAdd(&stg[SG_PIX + tid], (double)red[tid]);
  #pragma unroll
  for (int o = 32; o; o >>= 1) { mn = fminf(mn, __shfl_down(mn, o, 64)); mx = fmaxf(mx, __shfl_down(mx, o, 64)); }
  if ((tid & 63) == 0) { atomicMin(&stgu[1], fkey(mn)); atomicMax(&stgu[0], fkey(mx)); }
  float2* res = fft_core<1024, false>(shA, shB, tw, tid);
  float2* o = out + (size_t)row * 1024;
  for (int i = tid; i < 1024; i += 256) o[i] = res[skx(i)];
}

// pass B: plain load -> row FFT -> write / fused reductions
template<int N, bool INV>
__global__ __launch_bounds__(256) void k_passB(PBp p) {
  using FC = FftConst<N>;
  __shared__ float2 shA[FC::RPB][FC::BUF];
  __shared__ float2 shB[FC::RPB][FC::BUF];
  __shared__ float2 tw[N / 2];
  __shared__ float red[52];
  int tid = threadIdx.x;
  for (int k = tid; k < N / 2; k += 256) tw[k] = p.twg[k << (10 - FC::L2N)];
  int rl = tid / FC::TPR;
  int tr = tid % FC::TPR;
  int row = blockIdx.x * FC::RPB + rl;
  int plane = blockIdx.y;
  const float2* in = p.in[plane] + (size_t)row * N;
  float2* A = shA[rl];
  for (int i = tr; i < N; i += FC::TPR) A[skx(i)] = in[i];
  __syncthreads();
  float2* res = fft_core<N, INV>(A, shB[rl], tw, tr);
  constexpr float sc = INV ? 1.0f / (float)N : 1.0f;
  int wmode = p.wmode[plane];
  if (wmode == WB_WRITE || wmode == WB_WRITE_MAG || wmode == WB_WRITE_IM) {
    float2* o = p.out[plane] + (size_t)row * N;
    float a0 = 0.f, a1 = 0.f, a2 = 0.f;
    for (int i = tr; i < N; i += FC::TPR) {
      float2 v = res[skx(i)];
      v.x *= sc; v.y *= sc;
      o[i] = v;
      if (wmode == WB_WRITE_MAG) a0 += sqrtf(v.x * v.x + v.y * v.y);
      else if (wmode == WB_WRITE_IM) { float v2 = v.x * v.x; a0 += v2; a1 += v2 * v.x; a2 += v2 * v2; }
    }
    if (wmode == WB_WRITE_MAG) {
      float acc[1] = {a0}; blk_reduce<1>(acc, red);
      if (tid == 0) atomicAdd(p.red[plane], (double)red[0]);
    } else if (wmode == WB_WRITE_IM) {
      float acc[3] = {a0, a1, a2}; blk_reduce<3>(acc, red);
      if (tid < 3) atomicAdd(&p.red[plane][tid], (double)red[tid]);
    }
  } else if (wmode == WB_RED_HI) {
    float a0 = 0.f, a1 = 0.f;
    for (int i = tr; i < N; i += FC::TPR) {
      float v = res[skx(i)].x * sc;
      a0 += fabsf(v); a1 += v * v;
    }
    float acc[2] = {a0, a1}; blk_reduce<2>(acc, red);
    if (tid == 0) atomicAdd(p.red[plane], (double)red[0]);
    if (tid == 1) atomicAdd(p.red2, (double)red[1]);
  } else if (wmode == WB_RED_ABSRE) {
    float a0 = 0.f;
    for (int i = tr; i < N; i += FC::TPR) a0 += fabsf(res[skx(i)].x * sc);
    float acc[1] = {a0}; blk_reduce<1>(acc, red);
    if (tid == 0) atomicAdd(p.red[plane], (double)red[0]);
  } else if (wmode == WB_FWD_MASK) {
    float2* o1 = p.out[plane] + (size_t)row * N;
    float2* o2 = p.out2 + (size_t)row * N;
    int fx = sfreq(row, N);
    for (int i = tr; i < N; i += FC::TPR) {
      float2 v = res[skx(i)];
      int fy = sfreq(i, N);
      float rcv = d_rc(d_lograd(fy, fx, N));
      float hi = sqrtf(rcv), lo = sqrtf(fmaxf(1.0f - rcv, 0.0f));
      o1[i] = make_float2(v.x * hi, v.y * hi);
      o2[i] = make_float2(v.x * lo, v.y * lo);
    }
  } else {  // WB_PDOTS
    int b = p.aux[plane];
    float acc[13];
    #pragma unroll
    for (int k = 0; k < 13; k++) acc[k] = 0.f;
    for (int i = tr; i < N; i += FC::TPR) {
      float2 v = res[skx(i)];
      v.x *= sc; v.y *= sc;
      float mag = sqrtf(v.x * v.x + v.y * v.y);
      float rr = 0.f, ri = 0.f;
      if (mag > 0.f) { rr = (v.y * v.y - v.x * v.x) / mag; ri = 2.f * v.x * v.y / mag; }
      size_t idx = (size_t)row * N + i;
      #pragma unroll
      for (int c = 0; c < 4; c++) {
        float2 bv = p.Bp[c][idx];
        float am = sqrtf(bv.x * bv.x + bv.y * bv.y);
        acc[c] += am * mag;
        acc[4 + c] += bv.x * rr;
        acc[8 + c] += bv.x * ri;
      }
      acc[12] += mag;
    }
    blk_reduce<13>(acc, red);
    if (tid < 4) atomicAdd(&p.cx[tid * 4 + b], (double)red[tid]);
    else if (tid < 8) atomicAdd(&p.crx[(tid - 4) * 8 + b], (double)red[tid]);
    else if (tid < 12) atomicAdd(&p.crx[(tid - 8) * 8 + 4 + b], (double)red[tid]);
    else if (tid == 12) atomicAdd(p.red[plane], (double)red[12]);
  }
}

__global__ __launch_bounds__(256) void k_transpose(TPp p, int N) {
  __shared__ float2 tile[32][33];
  int z = blockIdx.z;
  const float2* in = p.src[z];
  float2* out = p.dst[z];
  int bx = blockIdx.x << 5, by = blockIdx.y << 5;
  int tx = threadIdx.x & 31, ty = threadIdx.x >> 5;
  for (int r = ty; r < 32; r += 8) tile[r][tx] = in[(size_t)(by + r) * N + bx + tx];
  __syncthreads();
  for (int r = ty; r < 32; r += 8) out[(size_t)(bx + r) * N + by + tx] = tile[tx][r];
}

// all 4 lowpass levels from L0 in one dispatch (cumulative masks)
__global__ __launch_bounds__(256) void k_ldown(const float2* __restrict__ L0,
                                               float2* __restrict__ L1, float2* __restrict__ L2,
                                               float2* __restrict__ L3, float2* __restrict__ L4) {
  int idx = blockIdx.x * 256 + threadIdx.x;
  int s, N, i;
  float2* dst;
  if (idx < 262144)      { s = 1; N = 512; i = idx;          dst = L1; }
  else if (idx < 327680) { s = 2; N = 256; i = idx - 262144; dst = L2; }
  else if (idx < 344064) { s = 3; N = 128; i = idx - 327680; dst = L3; }
  else if (idx < 348160) { s = 4; N = 64;  i = idx - 344064; dst = L4; }
  else return;
  int fy = sfreq(i / N, N), fx = sfreq(i % N, N);
  float m = 1.0f;
  for (int j = 1; j <= s; j++) m *= d_lo(fy, fx, 1024 >> j);
  int by = fy >= 0 ? fy : fy + 1024;
  int bx = fx >= 0 ? fx : fx + 1024;
  float2 v = L0[(size_t)by * 1024 + bx];
  if (s == 4 && i == 0) { dst[0] = make_float2(0.f, 0.f); return; }
  dst[i] = make_float2(v.x * m, v.y * m);
}

// ================= reductions / stats =================
__global__ __launch_bounds__(256) void k_init(double* stg, unsigned* stgu, float2* Wg) {
  int i = blockIdx.x * 256 + threadIdx.x;
  if (i < NSTG) stg[i] = 0.0;
  if (i == 0) { stgu[0] = 0u; stgu[1] = 0xFFFFFFFFu; }
  if (i < 512) {
    float a = TWOPI_F * (float)i * (1.0f / 1024.0f);
    float sv, cv; sincosf(a, &sv, &cv);
    Wg[i] = make_float2(cv, sv);
  }
}

// central 9x9 circular autocorrelation, RAW sums, register acc, double-buffered tiles.
// __launch_bounds__(256,2): 256-VGPR budget so acc[81] stays in registers (60-VGPR default spilled it).
__global__ __launch_bounds__(256, 2) void k_autocorr(ACp p, int H, double* acp) {
  __shared__ float tile[2][40][41];
  __shared__ float fred[4 * 81];
  const int plane = blockIdx.y;
  const float2* __restrict__ in = p.in[plane];
  const int mode = p.mode[plane];
  double* g = acp + ((size_t)((blockIdx.x & 3) * 21 + p.pi[plane])) * 81;
  float acc[81];
  #pragma unroll
  for (int k = 0; k < 81; k++) acc[k] = 0.f;
  const int tpr = H >> 5;
  const int nT = tpr * tpr;
  const int tid = threadIdx.x;
  const int tx4 = tid & 7, ty = tid >> 3;
  int cur = 0;
  {
    int ti = blockIdx.x;
    if (ti < nT) {
      int by = (ti / tpr) << 5, bx = (ti % tpr) << 5;
      #pragma unroll
      for (int k = 0; k < 7; k++) {
        int ii = tid + (k << 8);
        if (ii < 1600) {
          int r = ii / 40, c = ii - r * 40;
          int gy = (by + r - 4) & (H - 1), gx = (bx + c - 4) & (H - 1);
          float2 v = in[(size_t)gy * H + gx];
          tile[0][r][c] = mode ? sqrtf(v.x * v.x + v.y * v.y) : v.x;
        }
      }
    }
  }
  __syncthreads();
  for (int ti = blockIdx.x; ti < nT; ti += gridDim.x) {
    int tn = ti + gridDim.x;
    bool hn = tn < nT;
    float2 ld[7];
    if (hn) {
      int by = (tn / tpr) << 5, bx = (tn % tpr) << 5;
      #pragma unroll
      for (int k = 0; k < 7; k++) {
        int ii = tid + (k << 8);
        if (ii < 1600) {
          int r = ii / 40, c = ii - r * 40;
          int gy = (by + r - 4) & (H - 1), gx = (bx + c - 4) & (H - 1);
          ld[k] = in[(size_t)gy * H + gx];
        }
      }
    }
    float cen[4];
    #pragma unroll
    for (int c = 0; c < 4; c++) cen[c] = tile[cur][ty + 4][4 * tx4 + 4 + c];
    #pragma unroll
    for (int dy = -4; dy <= 4; dy++) {
      float r[12];
      #pragma unroll
      for (int j = 0; j < 12; j++) r[j] = tile[cur][ty + 4 + dy][4 * tx4 + j];
      #pragma unroll
      for (int dx = -4; dx <= 4; dx++) {
        float s = 0.f;
        #pragma unroll
        for (int c = 0; c < 4; c++) s += cen[c] * r[c + dx + 4];
        acc[(dy + 4) * 9 + (dx + 4)] += s;
      }
    }
    if (hn) {
      #pragma unroll
      for (int k = 0; k < 7; k++) {
        int ii = tid + (k << 8);
        if (ii < 1600) {
          int r = ii / 40, c = ii - r * 40;
          float2 v = ld[k];
          tile[cur ^ 1][r][c] = mode ? sqrtf(v.x * v.x + v.y * v.y) : v.x;
        }
      }
    }
    __syncthreads();
    cur ^= 1;
  }
  int wave = tid >> 6, lane = tid & 63;
  #pragma unroll
  for (int k = 0; k < 81; k++) {
    float x = acc[k];
    #pragma unroll
    for (int o = 32; o; o >>= 1) x += __shfl_down(x, o, 64);
    if (lane == 0) fred[wave * 81 + k] = x;
  }
  __syncthreads();
  for (int k = tid; k < 81; k += 256)
    atomicAdd(&g[k], (double)(fred[k] + fred[81 + k] + fred[162 + k] + fred[243 + k]));
}

// raw Grams of 4 band planes
__global__ __launch_bounds__(256, 4) void k_gram4(const float2* __restrict__ b0, const float2* __restrict__ b1,
                                                  const float2* __restrict__ b2, const float2* __restrict__ b3,
                                                  int n, double* c0out, double* crout) {
  __shared__ float red[128];
  float acc[32];
  #pragma unroll
  for (int k = 0; k < 32; k++) acc[k] = 0.f;
  for (int i = blockIdx.x * 256 + threadIdx.x; i < n; i += gridDim.x * 256) {
    float2 v0 = b0[i], v1 = b1[i], v2 = b2[i], v3 = b3[i];
    float a[4] = { sqrtf(v0.x * v0.x + v0.y * v0.y), sqrtf(v1.x * v1.x + v1.y * v1.y),
                   sqrtf(v2.x * v2.x + v2.y * v2.y), sqrtf(v3.x * v3.x + v3.y * v3.y) };
    float r[4] = { v0.x, v1.x, v2.x, v3.x };
    #pragma unroll
    for (int ii = 0; ii < 4; ii++)
      #pragma unroll
      for (int jj = 0; jj < 4; jj++) { acc[ii * 4 + jj] += a[ii] * a[jj]; acc[16 + ii * 4 + jj] += r[ii] * r[jj]; }
  }
  blk_reduce<32>(acc, red);
  int tid = threadIdx.x;
  if (tid < 16) atomicAdd(&c0out[tid], (double)red[tid]);
  else if (tid < 32) atomicAdd(&crout[tid - 16], (double)red[tid]);
}

__global__ __launch_bounds__(256, 4) void k_dots_rpar5(const float2* __restrict__ P,
                                                       const float2* __restrict__ b0, const float2* __restrict__ b1,
                                                       const float2* __restrict__ b2, const float2* __restrict__ b3,
                                                       double* crxB) {
  __shared__ float red[80];
  float acc[20];
  #pragma unroll
  for (int k = 0; k < 20; k++) acc[k] = 0.f;
  for (int i = blockIdx.x * 256 + threadIdx.x; i < 16384; i += gridDim.x * 256) {
    int y = i >> 7, x = i & 127;
    float tt[5];
    tt[0] = P[i].x;
    tt[1] = P[(y << 7) | ((x - 1) & 127)].x;
    tt[2] = P[(y << 7) | ((x + 1) & 127)].x;
    tt[3] = P[(((y - 1) & 127) << 7) | x].x;
    tt[4] = P[(((y + 1) & 127) << 7) | x].x;
    float r[4] = { b0[i].x, b1[i].x, b2[i].x, b3[i].x };
    #pragma unroll
    for (int a = 0; a < 4; a++)
      #pragma unroll
      for (int c = 0; c < 5; c++) acc[a * 5 + c] += r[a] * tt[c];
  }
  blk_reduce<20>(acc, red);
  int tid = threadIdx.x;
  if (tid < 20) atomicAdd(&crxB[(tid / 5) * 8 + (tid % 5)], (double)red[tid]);
}
__global__ __launch_bounds__(256, 4) void k_gram5(const float2* __restrict__ P, double* cr5) {
  __shared__ float red[100];
  float acc[25];
  #pragma unroll
  for (int k = 0; k < 25; k++) acc[k] = 0.f;
  for (int i = blockIdx.x * 256 + threadIdx.x; i < 16384; i += gridDim.x * 256) {
    int y = i >> 7, x = i & 127;
    float tt[5];
    tt[0] = P[i].x;
    tt[1] = P[(y << 7) | ((x - 1) & 127)].x;
    tt[2] = P[(y << 7) | ((x + 1) & 127)].x;
    tt[3] = P[(((y - 1) & 127) << 7) | x].x;
    tt[4] = P[(((y + 1) & 127) << 7) | x].x;
    #pragma unroll
    for (int a = 0; a < 5; a++)
      #pragma unroll
      for (int c = 0; c < 5; c++) acc[a * 5 + c] += tt[a] * tt[c];
  }
  blk_reduce<25>(acc, red);
  int tid = threadIdx.x;
  if (tid < 25) atomicAdd(&cr5[tid], (double)red[tid]);
}

// ================= finalize =================
__global__ __launch_bounds__(256) void k_finalize(const double* __restrict__ stg, const unsigned* __restrict__ stgu,
                                                  float* __restrict__ out) {
  int t = blockIdx.x * 256 + threadIdx.x;
  if (t >= 2456) return;
  const double N = 1048576.0;
  double m1 = stg[SG_PIX] / N, m2 = stg[SG_PIX + 1] / N;
  double vp = m2 - m1 * m1;
  if (t < 6) {
    double m3 = stg[SG_PIX + 2] / N, m4 = stg[SG_PIX + 3] / N;
    double cm3 = m3 - 3.0 * m1 * m2 + 2.0 * m1 * m1 * m1;
    double cm4 = m4 - 4.0 * m1 * m3 + 6.0 * m1 * m1 * m2 - 3.0 * m1 * m1 * m1 * m1;
    double r;
    if (t == 0) r = m1;
    else if (t == 1) r = vp * (N / (N - 1.0));
    else if (t == 2) r = cm3 / (vp * sqrt(vp));
    else if (t == 3) r = cm4 / (vp * vp);
    else if (t == 4) r = (double)funkey(stgu[1]);
    else r = (double)funkey(stgu[0]);
    out[t] = (float)r;
  } else if (t < 24) {
    int i = t - 6;
    double csz;
    if (i == 0) csz = 1048576.0;
    else if (i < 17) { int s = (i - 1) >> 2; double h = (double)(1024 >> s); csz = h * h; }
    else csz = 4096.0;
    out[t] = (float)(stg[SG_MAG + i] / csz);
  } else if (t < 1320) {
    int e = t - 24;
    int b = e & 3, s = (e >> 2) & 3, o = e >> 4;
    double h = (double)(1024 >> s); double csz = h * h;
    double m = stg[SG_MAG + 1 + 4 * s + b] / csz;
    int pi = s * 4 + b;
    double sum = stg[SG_ACP + (0 * 21 + pi) * 81 + o] + stg[SG_ACP + (1 * 21 + pi) * 81 + o]
               + stg[SG_ACP + (2 * 21 + pi) * 81 + o] + stg[SG_ACP + (3 * 21 + pi) * 81 + o];
    out[t] = (float)(sum / csz - m * m);
  } else if (t < 1330) {
    int kurt = (t >= 1325);
    int s = t - (kurt ? 1325 : 1320);
    double h = (double)(1024 >> s); double csz = h * h;
    double vari = stg[SG_IMM + s * 3] / csz;
    double var0 = vp * (N / (N - 1.0));
    double v = vari > 1e-12 ? vari : 1e-12;
    double r;
    if (vari / var0 > 1e-6)
      r = kurt ? (stg[SG_IMM + s * 3 + 2] / csz) / (v * v) : (stg[SG_IMM + s * 3 + 1] / csz) / (v * sqrt(v));
    else
      r = kurt ? 3.0 : 0.0;
    out[t] = (float)r;
  } else if (t < 1735) {
    int e = t - 1330;
    int s = e % 5, o = e / 5;
    double h = (double)(1024 >> s);
    int pi = 16 + s;
    double sum = stg[SG_ACP + (0 * 21 + pi) * 81 + o] + stg[SG_ACP + (1 * 21 + pi) * 81 + o]
               + stg[SG_ACP + (2 * 21 + pi) * 81 + o] + stg[SG_ACP + (3 * 21 + pi) * 81 + o];
    out[t] = (float)(sum / (h * h));
  } else if (t < 1815) {
    int e = t - 1735;
    int s = e % 5, o = e / 5;
    if (s < 4) {
      double h = (double)(1024 >> s); double csz = h * h;
      int i = o >> 2, j = o & 3;
      double mi = stg[SG_MAG + 1 + 4 * s + i] / csz;
      double mj = stg[SG_MAG + 1 + 4 * s + j] / csz;
      out[t] = (float)(stg[SG_C0 + s * 16 + o] / csz - mi * mj);
    } else out[t] = 0.0f;
  } else if (t < 1879) {
    int e = t - 1815;
    int s = e & 3, o = e >> 2;
    if (s < 3) {
      double h = (double)(1024 >> s); double csz = h * h;
      int c = o >> 2, b = o & 3;
      double mc = stg[SG_MAG + 1 + 4 * s + c] / csz;
      double pm = stg[SG_PMAG + 4 * s + b] / csz;
      out[t] = (float)(stg[SG_CX + s * 16 + o] / csz - mc * pm);
    } else out[t] = 0.0f;
  } else if (t < 2199) {
    int e = t - 1879;
    int s = e % 5, o = e / 5;
    int i = o >> 3, j = o & 7;
    float r = 0.0f;
    if (s < 4) { if (i < 4 && j < 4) { double h = (double)(1024 >> s); r = (float)(stg[SG_CR + s * 16 + i * 4 + j] / (h * h)); } }
    else { if (i < 5 && j < 5) r = (float)(stg[SG_CR5 + i * 5 + j] / 4096.0); }
    out[t] = r;
  } else if (t < 2455) {
    int e = t - 2199;
    int s = e & 3, o = e >> 2;
    int i = o >> 3, j = o & 7;
    float r = 0.0f;
    if (i < 4) {
      if (s < 3) { double h = (double)(1024 >> s); r = (float)(stg[SG_CRX + s * 32 + i * 8 + j] / (h * h)); }
      else if (j < 5) r = (float)(stg[SG_CRX + 96 + i * 8 + j] / 16384.0);
    }
    out[t] = r;
  } else {
    out[t] = (float)(stg[SG_HISQ] / N);
  }
}

// ================= host orchestration =================
static inline int rb(int n) { int b = (n + 255) / 256; return b > 256 ? 256 : b; }

struct Bufs {
  const float* img;
  float2* L[5];
  float2* Wg;
  double* stg; unsigned* stgu;
  float* out;
  char* w1;   // 40 MiB, 5 x 8MiB slots
  char* w2;   // 32 MiB, 4 x 8MiB slots
  char* l0raw;
};

template<int N>
static void scale_phase(const Bufs& B, int s, hipStream_t st) {
  constexpr int RPB = FftConst<N>::RPB;
  constexpr size_t PB = (size_t)N * N * 8;
  const int np = (N == 128) ? 6 : 5;
  // --- passA: {im, B0..3 [, Plo]} ---
  { PAp a{}; a.twg = B.Wg;
    a.in[0] = B.L[s]; a.mode[0] = MA_IM; a.aux[0] = 0;
    for (int b = 0; b < 4; b++) { a.in[1 + b] = B.L[s]; a.mode[1 + b] = MA_BAND; a.aux[1 + b] = b; }
    if (np == 6) { a.in[5] = B.L[4]; a.mode[5] = MA_EMBED_LO; a.aux[5] = 0; }
    for (int p = 0; p < np; p++) a.out[p] = (float2*)(B.w1 + p * PB);
    k_passA<N, true><<<dim3(N / RPB, np), 256, 0, st>>>(a); }
  // --- transpose ---
  float2* D[6];
  { TPp t{};
    for (int p = 0; p < np; p++) {
      D[p] = (N <= 512 || p < 4) ? (float2*)(B.w2 + p * PB) : (float2*)B.l0raw;
      t.src[p] = (const float2*)(B.w1 + p * PB); t.dst[p] = D[p];
    }
    k_transpose<<<dim3(N / 32, N / 32, np), 256, 0, st>>>(t, N); }
  // --- passB: spatial + fused stats ---
  { PBp bb{}; bb.twg = B.Wg;
    for (int p = 0; p < np; p++) { bb.in[p] = D[p]; bb.out[p] = (float2*)(B.w1 + p * PB); }
    bb.wmode[0] = WB_WRITE_IM; bb.red[0] = B.stg + SG_IMM + s * 3;
    for (int b = 0; b < 4; b++) { bb.wmode[1 + b] = WB_WRITE_MAG; bb.red[1 + b] = B.stg + SG_MAG + 1 + 4 * s + b; }
    if (np == 6) bb.wmode[5] = WB_WRITE;
    k_passB<N, true><<<dim3(N / RPB, np), 256, 0, st>>>(bb); }
  // --- autocorr (im + 4 bands), partitioned raw sums ---
  { ACp c{};
    c.in[0] = (const float2*)(B.w1); c.pi[0] = 16 + s; c.mode[0] = 0;
    for (int b = 0; b < 4; b++) { c.in[1 + b] = (const float2*)(B.w1 + (1 + b) * PB); c.pi[1 + b] = s * 4 + b; c.mode[1 + b] = 1; }
    int nT = (N / 32) * (N / 32);
    k_autocorr<<<dim3(nT > 256 ? 256 : nT, 5), 256, 0, st>>>(c, N, B.stg + SG_ACP); }
  // --- raw gram ---
  k_gram4<<<rb(N * N), 256, 0, st>>>((const float2*)(B.w1 + PB), (const float2*)(B.w1 + 2 * PB),
                                     (const float2*)(B.w1 + 3 * PB), (const float2*)(B.w1 + 4 * PB),
                                     N * N, B.stg + SG_C0 + s * 16, B.stg + SG_CR + s * 16);
  if (s < 3) {
    // --- parents: one 4-plane passA, then 2x (transpose + pdots passB) ---
    { PAp a{}; a.twg = B.Wg;
      for (int b = 0; b < 4; b++) { a.in[b] = B.L[s + 1]; a.mode[b] = MA_EMBED_BAND; a.aux[b] = b; a.out[b] = (float2*)(B.w2 + b * PB); }
      k_passA<N, true><<<dim3(N / RPB, 4), 256, 0, st>>>(a); }
    char* td0; char* td1;
    if (N == 1024) { td0 = B.l0raw; td1 = B.w1; }            // L0 and im-slot free by now
    else { td0 = B.w2 + 4 * PB; td1 = B.w2 + 5 * PB; }
    for (int pr = 0; pr < 2; pr++) {
      { TPp t{};
        t.src[0] = (const float2*)(B.w2 + (2 * pr) * PB); t.dst[0] = (float2*)td0;
        t.src[1] = (const float2*)(B.w2 + (2 * pr + 1) * PB); t.dst[1] = (float2*)td1;
        k_transpose<<<dim3(N / 32, N / 32, 2), 256, 0, st>>>(t, N); }
      { PBp bb{}; bb.twg = B.Wg;
        bb.in[0] = (const float2*)td0; bb.in[1] = (const float2*)td1;
        for (int k = 0; k < 2; k++) { int b = pr * 2 + k; bb.wmode[k] = WB_PDOTS; bb.aux[k] = b; bb.red[k] = B.stg + SG_PMAG + 4 * s + b; }
        for (int cc = 0; cc < 4; cc++) bb.Bp[cc] = (const float2*)(B.w1 + (1 + cc) * PB);
        bb.cx = B.stg + SG_CX + s * 16; bb.crx = B.stg + SG_CRX + s * 32;
        k_passB<N, true><<<dim3(N / RPB, 2), 256, 0, st>>>(bb); }
    }
  } else {
    k_dots_rpar5<<<64, 256, 0, st>>>((const float2*)(B.w1 + 5 * PB),
                                     (const float2*)(B.w1 + PB), (const float2*)(B.w1 + 2 * PB),
                                     (const float2*)(B.w1 + 3 * PB), (const float2*)(B.w1 + 4 * PB),
                                     B.stg + SG_CRX + 96);
    k_gram5<<<64, 256, 0, st>>>((const float2*)(B.w1 + 5 * PB), B.stg + SG_CR5);
  }
}

extern "C" void kernel_launch(void* const* d_in, const int* in_sizes, int n_in,
                              void* d_out, int out_size, void* d_ws, size_t ws_size,
                              hipStream_t stream) {
  (void)in_sizes; (void)n_in; (void)out_size;
  if (ws_size < 87031808ull) return;   // 83 MiB
  char* w = (char*)d_ws;
  Bufs B;
  B.img = (const float*)d_in[0];
  B.out = (float*)d_out;
  B.L[0] = (float2*)(w + 0ull);
  B.L[1] = (float2*)(w + 8388608ull);
  B.L[2] = (float2*)(w + 10485760ull);
  B.L[3] = (float2*)(w + 11010048ull);
  B.L[4] = (float2*)(w + 11141120ull);
  B.Wg   = (float2*)(w + 11173888ull);
  B.stg  = (double*)(w + 11177984ull);
  B.stgu = (unsigned*)(B.stg + NSTG);
  B.w1   = w + 11534336ull;            // 40 MiB
  B.w2   = w + 53477376ull;            // 32 MiB
  B.l0raw = w;                          // L0 region, reused once free
  hipStream_t st = stream;
  double* stg = B.stg;
  constexpr size_t PB8 = 8388608ull;

  k_init<<<29, 256, 0, st>>>(stg, B.stgu, B.Wg);

  // forward fft2 with fused pixel raw moments: img -> rows-FFT (w1 s0), transpose, masked spectra
  k_fwdA<<<1024, 256, 0, st>>>(B.img, (float2*)(B.w1), B.Wg, stg, B.stgu);
  { TPp t{}; t.src[0] = (const float2*)(B.w1); t.dst[0] = (float2*)(B.w2);
    k_transpose<<<dim3(32, 32, 1), 256, 0, st>>>(t, 1024); }
  { PBp bb{}; bb.twg = B.Wg; bb.in[0] = (const float2*)(B.w2); bb.wmode[0] = WB_FWD_MASK;
    bb.out[0] = (float2*)(B.w1 + PB8); bb.out2 = B.L[0];
    k_passB<1024, false><<<dim3(1024, 1), 256, 0, st>>>(bb); }

  // hi residual: ifft2 of hi-spec, reduce-only (sum|re|, re^2)
  { PAp a{}; a.twg = B.Wg; a.in[0] = (const float2*)(B.w1 + PB8); a.mode[0] = MA_C2; a.aux[0] = 0;
    a.out[0] = (float2*)(B.w1);
    k_passA<1024, true><<<dim3(1024, 1), 256, 0, st>>>(a); }
  { TPp t{}; t.src[0] = (const float2*)(B.w1); t.dst[0] = (float2*)(B.w2);
    k_transpose<<<dim3(32, 32, 1), 256, 0, st>>>(t, 1024); }
  { PBp bb{}; bb.twg = B.Wg; bb.in[0] = (const float2*)(B.w2); bb.wmode[0] = WB_RED_HI;
    bb.red[0] = stg + SG_MAG; bb.red2 = stg + SG_HISQ;
    k_passB<1024, true><<<dim3(1024, 1), 256, 0, st>>>(bb); }

  // lowpass chain, single dispatch
  k_ldown<<<1360, 256, 0, st>>>(B.L[0], B.L[1], B.L[2], B.L[3], B.L[4]);

  // size-64 batch: {lo-resid (plain ifft of L4), imF4 = L4*lo0}
  {
    constexpr size_t PB = 64ull * 64ull * 8ull;
    constexpr int RPB = FftConst<64>::RPB;
    { PAp a{}; a.twg = B.Wg;
      a.in[0] = B.L[4]; a.mode[0] = MA_C2; a.aux[0] = 0; a.out[0] = (float2*)(B.w1);
      a.in[1] = B.L[4]; a.mode[1] = MA_IMF4; a.aux[1] = 0; a.out[1] = (float2*)(B.w1 + PB);
      k_passA<64, true><<<dim3(64 / RPB, 2), 256, 0, st>>>(a); }
    { TPp t{};
      t.src[0] = (const float2*)(B.w1); t.dst[0] = (float2*)(B.w2);
      t.src[1] = (const float2*)(B.w1 + PB); t.dst[1] = (float2*)(B.w2 + PB);
      k_transpose<<<dim3(2, 2, 2), 256, 0, st>>>(t, 64); }
    { PBp bb{}; bb.twg = B.Wg;
      bb.in[0] = (const float2*)(B.w2); bb.wmode[0] = WB_RED_ABSRE; bb.red[0] = stg + SG_MAG + 17;
      bb.in[1] = (const float2*)(B.w2 + PB); bb.wmode[1] = WB_WRITE_IM; bb.red[1] = stg + SG_IMM + 12;
      bb.out[1] = (float2*)(B.w1 + PB);
      k_passB<64, true><<<dim3(64 / RPB, 2), 256, 0, st>>>(bb); }
    { ACp c{}; c.in[0] = (const float2*)(B.w1 + PB); c.pi[0] = 20; c.mode[0] = 0;
      k_autocorr<<<dim3(4, 1), 256, 0, st>>>(c, 64, stg + SG_ACP); }
  }

  // per-scale batches
  scale_phase<128>(B, 3, st);
  scale_phase<256>(B, 2, st);
  scale_phase<512>(B, 1, st);
  scale_phase<1024>(B, 0, st);

  k_finalize<<<10, 256, 0, st>>>(stg, B.stgu, B.out);
}

// Round 7
// 817.928 us; speedup vs baseline: 1.1648x; 1.1648x over previous
//
#include <hip/hip_runtime.h>
#include <math.h>

#define PI_F      3.14159265358979323846f
#define TWOPI_F   6.28318530717958647692f
#define HALFPI_F  1.57079632679489661923f
#define ANG_F     0.8944271909999159f

// ---- staging layout (doubles) ----
#define SG_PIX   0      // RAW: sum x, x^2, x^3, x^4
#define SG_MAG   4      // 18 magnitude sums
#define SG_HISQ  22     // sum hi^2
#define SG_PMAG  23     // 12 parent-mag sums (s=0..2, b=0..3)
#define SG_IMM   35     // 5 x (sum im^2, im^3, im^4)
#define SG_ACP   50     // [4 partitions][21 planes][41] raw symmetric ac sums (planes: 0..15 = ACE(s,b), 16..20 = ACR(s))
#define SG_C0    3494   // [4][16]     raw
#define SG_CR    3558   // [4][16]
#define SG_CX    3622   // [3][16]     raw
#define SG_CRX   3670   // [4][4*8]
#define SG_CR5   3798   // [25]
#define NSTG     3823

enum { MA_C2 = 0, MA_REAL, MA_BAND, MA_EMBED_BAND, MA_EMBED_LO, MA_IMF4, MA_IM };
enum { WB_WRITE = 0, WB_WRITE_MAG, WB_WRITE_IM, WB_RED_HI, WB_RED_ABSRE, WB_FWD_MASK, WB_PDOTS };

__device__ __forceinline__ int sfreq(int k, int H) { return (k < (H >> 1)) ? k : k - H; }
__device__ __forceinline__ int skx(int i) { return i + (i >> 4); }   // LDS bank skew

__device__ __forceinline__ float d_lograd(int fy, int fx, int H) {
  float cy = (float)fy * (2.0f / (float)H);
  float cx = (float)fx * (2.0f / (float)H);
  float rad = sqrtf(cx * cx + cy * cy);
  if (fy == 0 && fx == 0) rad = 2.0f / (float)H;   // reference DC hack
  return log2f(rad);
}
__device__ __forceinline__ float d_angle(int fy, int fx, int H) {
  return atan2f((float)fy * (2.0f / (float)H), (float)fx * (2.0f / (float)H));
}
__device__ __forceinline__ float d_rc(float x) {
  float c = fminf(fmaxf(-x, 0.0f), 1.0f);
  float t = cosf(0.5f * PI_F * c);
  return t * t;
}
__device__ __forceinline__ float d_alfa(float ang, int b) {
  float bc = (b == 0) ? 0.0f : (b == 1) ? 0.78539816339744830962f
           : (b == 2) ? 1.57079632679489661923f : 2.35619449019234492885f;
  float t = (PI_F + ang) - bc;
  float m = fmodf(t, TWOPI_F);
  if (m < 0.0f) m += TWOPI_F;
  return m - PI_F;
}
__device__ __forceinline__ float d_cos3(float a) { float c = cosf(a); return ANG_F * c * c * c; }
__device__ __forceinline__ float d_amaskC(float ang, int b) {
  float alfa = d_alfa(ang, b);
  float A = d_cos3(alfa);
  return (fabsf(alfa) < HALFPI_F) ? 2.0f * A : 0.0f;
}
__device__ __forceinline__ float d_lo(int fy, int fx, int H) {
  return sqrtf(fmaxf(1.0f - d_rc(d_lograd(fy, fx, H)), 0.0f));
}
// recon mask at native size H
__device__ __forceinline__ float d_mm(int fy, int fx, int H) {
  float lr = d_lograd(fy, fx, H);
  float hm2 = d_rc(lr + 1.0f);
  float lo0 = sqrtf(fmaxf(1.0f - d_rc(lr), 0.0f));
  float ang1 = d_angle(fy, fx, H);
  int gfy = (fy == -(H >> 1)) ? fy : -fy;
  int gfx = (fx == -(H >> 1)) ? fx : -fx;
  float ang2 = d_angle(gfy, gfx, H);
  float msum = 0.0f;
  #pragma unroll
  for (int b4 = 0; b4 < 4; b4++) {
    float a1 = d_alfa(ang1, b4), a2 = d_alfa(ang2, b4);
    float A1 = d_cos3(a1), A2 = d_cos3(a2);
    float T1 = (fabsf(a1) < HALFPI_F) ? A1 : 0.0f;
    float T2 = (fabsf(a2) < HALFPI_F) ? A2 : 0.0f;
    msum += A1 * (T1 - T2);
  }
  return lo0 * hm2 * msum;
}
// accumulated im-chain mask at scale with native size N (N>=128)
template<int N>
__device__ __forceinline__ float d_G(int fy, int fx) {
  float g = d_mm(fy, fx, N);
  float chain = 1.0f;
  #pragma unroll
  for (int Nj = (N >> 1); Nj >= 64; Nj >>= 1) {
    int h = Nj >> 1;
    if (fy < -h || fy >= h || fx < -h || fx >= h) break;
    chain *= d_lo(fy, fx, Nj);
    if (Nj > 64) g += chain * d_mm(fy, fx, Nj);
    else g += chain * d_lo(fy, fx, 64);
  }
  if (fy == 0 && fx == 0) g = 0.0f;
  return g;
}
__device__ __forceinline__ unsigned fkey(float f) {
  unsigned u = __float_as_uint(f);
  return (u & 0x80000000u) ? ~u : (u | 0x80000000u);
}
__device__ __forceinline__ float funkey(unsigned k) {
  return (k & 0x80000000u) ? __uint_as_float(k & 0x7FFFFFFFu) : __uint_as_float(~k);
}
// map full 9x9 offset index (0..80) to symmetric 41-index
__device__ __forceinline__ int sidx(int o) {
  int dy = o / 9 - 4, dx = o - (o / 9) * 9 - 4;
  if (dy < 0 || (dy == 0 && dx < 0)) { dy = -dy; dx = -dx; }
  return (dy == 0) ? dx : 5 + (dy - 1) * 9 + dx + 4;
}

template<int K>
__device__ __forceinline__ void blk_reduce(float* v, float* red) {
  int tid = threadIdx.x, wave = tid >> 6, lane = tid & 63;
  #pragma unroll
  for (int k = 0; k < K; k++) {
    float x = v[k];
    #pragma unroll
    for (int o = 32; o; o >>= 1) x += __shfl_down(x, o, 64);
    if (lane == 0) red[wave * K + k] = x;
  }
  __syncthreads();
  if (tid < K) red[tid] = red[tid] + red[K + tid] + red[2 * K + tid] + red[3 * K + tid];
}

// ================= FFT core (Stockham, radix-4 with leading radix-2) =================
template<int N> struct FftConst {
  static constexpr int L2N = (N == 64) ? 6 : (N == 128) ? 7 : (N == 256) ? 8 : (N == 512) ? 9 : 10;
  static constexpr int TPR = (N / 4 >= 256) ? 256 : ((N / 4 < 16) ? 16 : N / 4);
  static constexpr int RPB = 256 / TPR;
  static constexpr int BUF = N + (N >> 4);
};

template<int N, bool INV>
__device__ __forceinline__ float2* fft_core(float2* A, float2* B, const float2* tw, int tr) {
  constexpr int TPR = FftConst<N>::TPR;
  constexpr int L2N = FftConst<N>::L2N;
  float2* src = A; float2* dst = B;
  if constexpr (L2N & 1) {
    for (int t = tr; t < (N >> 1); t += TPR) {
      float2 w = tw[t];
      float cv = w.x, sv = INV ? w.y : -w.y;
      float2 a = src[skx(t)];
      float2 b = src[skx(t + (N >> 1))];
      float dx = a.x - b.x, dy = a.y - b.y;
      dst[skx(2 * t)] = make_float2(a.x + b.x, a.y + b.y);
      dst[skx(2 * t + 1)] = make_float2(dx * cv - dy * sv, dx * sv + dy * cv);
    }
    __syncthreads();
    float2* tmp = src; src = dst; dst = tmp;
  }
  #pragma unroll
  for (int st = (L2N & 1); st < L2N; st += 2) {
    for (int t = tr; t < (N >> 2); t += TPR) {
      int p = t >> st;
      int q = t & ((1 << st) - 1);
      int i0 = q + (p << st);
      float2 x0 = src[skx(i0)];
      float2 x1 = src[skx(i0 + (N >> 2))];
      float2 x2 = src[skx(i0 + (N >> 1))];
      float2 x3 = src[skx(i0 + 3 * (N >> 2))];
      float2 w = tw[p << st];
      float c1 = w.x, s1 = INV ? w.y : -w.y;
      float c2 = c1 * c1 - s1 * s1, s2 = 2.f * c1 * s1;
      float c3 = c2 * c1 - s2 * s1, s3 = c2 * s1 + s2 * c1;
      float e0x = x0.x + x2.x, e0y = x0.y + x2.y;
      float e1x = x0.x - x2.x, e1y = x0.y - x2.y;
      float o0x = x1.x + x3.x, o0y = x1.y + x3.y;
      float d1x = x1.x - x3.x, d1y = x1.y - x3.y;
      float o1x, o1y;
      if constexpr (INV) { o1x = -d1y; o1y = d1x; }
      else               { o1x = d1y;  o1y = -d1x; }
      float t1x = e1x + o1x, t1y = e1y + o1y;
      float t2x = e0x - o0x, t2y = e0y - o0y;
      float t3x = e1x - o1x, t3y = e1y - o1y;
      int o = q + (p << (st + 2));
      int s = 1 << st;
      dst[skx(o)]         = make_float2(e0x + o0x, e0y + o0y);
      dst[skx(o + s)]     = make_float2(t1x * c1 - t1y * s1, t1x * s1 + t1y * c1);
      dst[skx(o + 2 * s)] = make_float2(t2x * c2 - t2y * s2, t2x * s2 + t2y * c2);
      dst[skx(o + 3 * s)] = make_float2(t3x * c3 - t3y * s3, t3x * s3 + t3y * c3);
    }
    __syncthreads();
    float2* tmp = src; src = dst; dst = tmp;
  }
  return src;
}

struct PAp {
  const float2* in[6];
  float2* out[6];
  const float2* twg;
  int mode[6];
  int aux[6];
};
struct PBp {
  const float2* in[6];
  float2* out[6];
  float2* out2;
  const float2* Bp[4];
  double* red[6];
  double* red2;
  double* cx;
  double* crx;
  const float2* twg;
  int wmode[6];
  int aux[6];
};
struct TPp { const float2* src[6]; float2* dst[6]; };
struct ACp { const float2* in[5]; int pi[5]; int mode[5]; };

template<int N, int MODE>
__device__ __forceinline__ float2 loadA(const float2* in, int row, int i, int b) {
  if constexpr (MODE == MA_C2) {
    return in[(size_t)row * N + i];
  } else if constexpr (MODE == MA_REAL) {
    const float* f = (const float*)in;
    return make_float2(f[(size_t)row * N + i], 0.0f);
  } else if constexpr (MODE == MA_BAND) {
    int fy = sfreq(i, N), fx = sfreq(row, N);
    float m = sqrtf(d_rc(d_lograd(fy, fx, N) + 1.0f)) * d_amaskC(d_angle(fy, fx, N), b);
    float2 l = in[(size_t)row * N + i];
    return make_float2(-l.y * m, l.x * m);
  } else if constexpr (MODE == MA_EMBED_BAND) {
    int fy = sfreq(i, N), fx = sfreq(row, N);
    int q = N >> 2, h2 = N >> 1;
    if (fy < -q || fy >= q || fx < -q || fx >= q) return make_float2(0.f, 0.f);
    int U = fx >= 0 ? fx : fx + h2, V = fy >= 0 ? fy : fy + h2;
    float m = sqrtf(d_rc(d_lograd(fy, fx, h2) + 1.0f)) * d_amaskC(d_angle(fy, fx, h2), b);
    float2 l = in[(size_t)U * h2 + V];
    return make_float2(-l.y * m, l.x * m);
  } else if constexpr (MODE == MA_EMBED_LO) {
    int fy = sfreq(i, N), fx = sfreq(row, N);
    int q = N >> 2, h2 = N >> 1;
    if (fy < -q || fy >= q || fx < -q || fx >= q) return make_float2(0.f, 0.f);
    int U = fx >= 0 ? fx : fx + h2, V = fy >= 0 ? fy : fy + h2;
    return in[(size_t)U * h2 + V];
  } else if constexpr (MODE == MA_IMF4) {
    int fy = sfreq(i, N), fx = sfreq(row, N);
    float lo = d_lo(fy, fx, N);
    float2 v = in[(size_t)row * N + i];
    return make_float2(v.x * lo, v.y * lo);
  } else {  // MA_IM
    int fy = sfreq(i, N), fx = sfreq(row, N);
    float g = d_G<N>(fy, fx);
    float2 l = in[(size_t)row * N + i];
    return make_float2(l.x * g, l.y * g);
  }
}

// pass A: fused load op -> row FFT -> write
template<int N, bool INV>
__global__ __launch_bounds__(256) void k_passA(PAp p) {
  using FC = FftConst<N>;
  __shared__ float2 shA[FC::RPB][FC::BUF];
  __shared__ float2 shB[FC::RPB][FC::BUF];
  __shared__ float2 tw[N / 2];
  int tid = threadIdx.x;
  for (int k = tid; k < N / 2; k += 256) tw[k] = p.twg[k << (10 - FC::L2N)];
  int rl = tid / FC::TPR;
  int tr = tid % FC::TPR;
  int row = blockIdx.x * FC::RPB + rl;
  int plane = blockIdx.y;
  const float2* in = p.in[plane];
  int mode = p.mode[plane];
  int b = p.aux[plane];
  float2* A = shA[rl];
  switch (mode) {
    case MA_C2:         for (int i = tr; i < N; i += FC::TPR) A[skx(i)] = loadA<N, MA_C2>(in, row, i, b); break;
    case MA_REAL:       for (int i = tr; i < N; i += FC::TPR) A[skx(i)] = loadA<N, MA_REAL>(in, row, i, b); break;
    case MA_BAND:       for (int i = tr; i < N; i += FC::TPR) A[skx(i)] = loadA<N, MA_BAND>(in, row, i, b); break;
    case MA_EMBED_BAND: for (int i = tr; i < N; i += FC::TPR) A[skx(i)] = loadA<N, MA_EMBED_BAND>(in, row, i, b); break;
    case MA_EMBED_LO:   for (int i = tr; i < N; i += FC::TPR) A[skx(i)] = loadA<N, MA_EMBED_LO>(in, row, i, b); break;
    case MA_IMF4:       for (int i = tr; i < N; i += FC::TPR) A[skx(i)] = loadA<N, MA_IMF4>(in, row, i, b); break;
    default:            for (int i = tr; i < N; i += FC::TPR) A[skx(i)] = loadA<N, MA_IM>(in, row, i, b); break;
  }
  __syncthreads();
  float2* res = fft_core<N, INV>(A, shB[rl], tw, tr);
  constexpr float sc = INV ? 1.0f / (float)N : 1.0f;
  float2* o = p.out[plane] + (size_t)row * N;
  for (int i = tr; i < N; i += FC::TPR) {
    float2 v = res[skx(i)];
    o[i] = make_float2(v.x * sc, v.y * sc);
  }
}

// forward passA over the raw image with fused raw pixel moments + min/max
__global__ __launch_bounds__(256) void k_fwdA(const float* __restrict__ img, float2* __restrict__ out,
                                              const float2* __restrict__ twg, double* stg, unsigned* stgu) {
  using FC = FftConst<1024>;
  __shared__ float2 shA[FC::BUF];
  __shared__ float2 shB[FC::BUF];
  __shared__ float2 tw[512];
  __shared__ float red[16];
  int tid = threadIdx.x;
  for (int k = tid; k < 512; k += 256) tw[k] = twg[k];
  int row = blockIdx.x;
  float s1 = 0.f, s2 = 0.f, s3 = 0.f, s4 = 0.f;
  float mn = 3.402823466e38f, mx = -3.402823466e38f;
  for (int i = tid; i < 1024; i += 256) {
    float x = img[(size_t)row * 1024 + i];
    shA[skx(i)] = make_float2(x, 0.f);
    float x2 = x * x;
    s1 += x; s2 += x2; s3 += x2 * x; s4 += x2 * x2;
    mn = fminf(mn, x); mx = fmaxf(mx, x);
  }
  float accv[4] = {s1, s2, s3, s4};
  blk_reduce<4>(accv, red);
  if (tid < 4) atomicAdd(&stg[SG_PIX + tid], (double)red[tid]);
  #pragma unroll
  for (int o = 32; o; o >>= 1) { mn = fminf(mn, __shfl_down(mn, o, 64)); mx = fmaxf(mx, __shfl_down(mx, o, 64)); }
  if ((tid & 63) == 0) { atomicMin(&stgu[1], fkey(mn)); atomicMax(&stgu[0], fkey(mx)); }
  float2* res = fft_core<1024, false>(shA, shB, tw, tid);
  float2* o = out + (size_t)row * 1024;
  for (int i = tid; i < 1024; i += 256) o[i] = res[skx(i)];
}

// pass B: plain load -> row FFT -> write / fused reductions
template<int N, bool INV>
__global__ __launch_bounds__(256) void k_passB(PBp p) {
  using FC = FftConst<N>;
  __shared__ float2 shA[FC::RPB][FC::BUF];
  __shared__ float2 shB[FC::RPB][FC::BUF];
  __shared__ float2 tw[N / 2];
  __shared__ float red[52];
  int tid = threadIdx.x;
  for (int k = tid; k < N / 2; k += 256) tw[k] = p.twg[k << (10 - FC::L2N)];
  int rl = tid / FC::TPR;
  int tr = tid % FC::TPR;
  int row = blockIdx.x * FC::RPB + rl;
  int plane = blockIdx.y;
  const float2* in = p.in[plane] + (size_t)row * N;
  float2* A = shA[rl];
  for (int i = tr; i < N; i += FC::TPR) A[skx(i)] = in[i];
  __syncthreads();
  float2* res = fft_core<N, INV>(A, shB[rl], tw, tr);
  constexpr float sc = INV ? 1.0f / (float)N : 1.0f;
  int wmode = p.wmode[plane];
  if (wmode == WB_WRITE || wmode == WB_WRITE_MAG || wmode == WB_WRITE_IM) {
    float2* o = p.out[plane] + (size_t)row * N;
    float a0 = 0.f, a1 = 0.f, a2 = 0.f;
    for (int i = tr; i < N; i += FC::TPR) {
      float2 v = res[skx(i)];
      v.x *= sc; v.y *= sc;
      o[i] = v;
      if (wmode == WB_WRITE_MAG) a0 += sqrtf(v.x * v.x + v.y * v.y);
      else if (wmode == WB_WRITE_IM) { float v2 = v.x * v.x; a0 += v2; a1 += v2 * v.x; a2 += v2 * v2; }
    }
    if (wmode == WB_WRITE_MAG) {
      float acc[1] = {a0}; blk_reduce<1>(acc, red);
      if (tid == 0) atomicAdd(p.red[plane], (double)red[0]);
    } else if (wmode == WB_WRITE_IM) {
      float acc[3] = {a0, a1, a2}; blk_reduce<3>(acc, red);
      if (tid < 3) atomicAdd(&p.red[plane][tid], (double)red[tid]);
    }
  } else if (wmode == WB_RED_HI) {
    float a0 = 0.f, a1 = 0.f;
    for (int i = tr; i < N; i += FC::TPR) {
      float v = res[skx(i)].x * sc;
      a0 += fabsf(v); a1 += v * v;
    }
    float acc[2] = {a0, a1}; blk_reduce<2>(acc, red);
    if (tid == 0) atomicAdd(p.red[plane], (double)red[0]);
    if (tid == 1) atomicAdd(p.red2, (double)red[1]);
  } else if (wmode == WB_RED_ABSRE) {
    float a0 = 0.f;
    for (int i = tr; i < N; i += FC::TPR) a0 += fabsf(res[skx(i)].x * sc);
    float acc[1] = {a0}; blk_reduce<1>(acc, red);
    if (tid == 0) atomicAdd(p.red[plane], (double)red[0]);
  } else if (wmode == WB_FWD_MASK) {
    float2* o1 = p.out[plane] + (size_t)row * N;
    float2* o2 = p.out2 + (size_t)row * N;
    int fx = sfreq(row, N);
    for (int i = tr; i < N; i += FC::TPR) {
      float2 v = res[skx(i)];
      int fy = sfreq(i, N);
      float rcv = d_rc(d_lograd(fy, fx, N));
      float hi = sqrtf(rcv), lo = sqrtf(fmaxf(1.0f - rcv, 0.0f));
      o1[i] = make_float2(v.x * hi, v.y * hi);
      o2[i] = make_float2(v.x * lo, v.y * lo);
    }
  } else {  // WB_PDOTS
    int b = p.aux[plane];
    float acc[13];
    #pragma unroll
    for (int k = 0; k < 13; k++) acc[k] = 0.f;
    for (int i = tr; i < N; i += FC::TPR) {
      float2 v = res[skx(i)];
      v.x *= sc; v.y *= sc;
      float mag = sqrtf(v.x * v.x + v.y * v.y);
      float rr = 0.f, ri = 0.f;
      if (mag > 0.f) { rr = (v.y * v.y - v.x * v.x) / mag; ri = 2.f * v.x * v.y / mag; }
      size_t idx = (size_t)row * N + i;
      #pragma unroll
      for (int c = 0; c < 4; c++) {
        float2 bv = p.Bp[c][idx];
        float am = sqrtf(bv.x * bv.x + bv.y * bv.y);
        acc[c] += am * mag;
        acc[4 + c] += bv.x * rr;
        acc[8 + c] += bv.x * ri;
      }
      acc[12] += mag;
    }
    blk_reduce<13>(acc, red);
    if (tid < 4) atomicAdd(&p.cx[tid * 4 + b], (double)red[tid]);
    else if (tid < 8) atomicAdd(&p.crx[(tid - 4) * 8 + b], (double)red[tid]);
    else if (tid < 12) atomicAdd(&p.crx[(tid - 8) * 8 + 4 + b], (double)red[tid]);
    else if (tid == 12) atomicAdd(p.red[plane], (double)red[12]);
  }
}

__global__ __launch_bounds__(256) void k_transpose(TPp p, int N) {
  __shared__ float2 tile[32][33];
  int z = blockIdx.z;
  const float2* in = p.src[z];
  float2* out = p.dst[z];
  int bx = blockIdx.x << 5, by = blockIdx.y << 5;
  int tx = threadIdx.x & 31, ty = threadIdx.x >> 5;
  for (int r = ty; r < 32; r += 8) tile[r][tx] = in[(size_t)(by + r) * N + bx + tx];
  __syncthreads();
  for (int r = ty; r < 32; r += 8) out[(size_t)(bx + r) * N + by + tx] = tile[tx][r];
}

// all 4 lowpass levels from L0 in one dispatch (cumulative masks)
__global__ __launch_bounds__(256) void k_ldown(const float2* __restrict__ L0,
                                               float2* __restrict__ L1, float2* __restrict__ L2,
                                               float2* __restrict__ L3, float2* __restrict__ L4) {
  int idx = blockIdx.x * 256 + threadIdx.x;
  int s, N, i;
  float2* dst;
  if (idx < 262144)      { s = 1; N = 512; i = idx;          dst = L1; }
  else if (idx < 327680) { s = 2; N = 256; i = idx - 262144; dst = L2; }
  else if (idx < 344064) { s = 3; N = 128; i = idx - 327680; dst = L3; }
  else if (idx < 348160) { s = 4; N = 64;  i = idx - 344064; dst = L4; }
  else return;
  int fy = sfreq(i / N, N), fx = sfreq(i % N, N);
  float m = 1.0f;
  for (int j = 1; j <= s; j++) m *= d_lo(fy, fx, 1024 >> j);
  int by = fy >= 0 ? fy : fy + 1024;
  int bx = fx >= 0 ? fx : fx + 1024;
  float2 v = L0[(size_t)by * 1024 + bx];
  if (s == 4 && i == 0) { dst[0] = make_float2(0.f, 0.f); return; }
  dst[i] = make_float2(v.x * m, v.y * m);
}

// ================= reductions / stats =================
__global__ __launch_bounds__(256) void k_init(double* stg, unsigned* stgu, float2* Wg) {
  int i = blockIdx.x * 256 + threadIdx.x;
  if (i < NSTG) stg[i] = 0.0;
  if (i == 0) { stgu[0] = 0u; stgu[1] = 0xFFFFFFFFu; }
  if (i < 512) {
    float a = TWOPI_F * (float)i * (1.0f / 1024.0f);
    float sv, cv; sincosf(a, &sv, &cv);
    Wg[i] = make_float2(cv, sv);
  }
}

// central 9x9 circular autocorrelation, RAW sums, symmetry-halved (41 offsets).
// Full-torus circular ac is exactly even: ac(d) == ac(-d); mirror in finalize.
// acc[41]+window ~72 live VGPRs -> no spill at (256,3) cap (~170).
__global__ __launch_bounds__(256, 3) void k_autocorr(ACp p, int H, double* acp) {
  __shared__ float tile[40][41];
  __shared__ float fred[4 * 41];
  const int plane = blockIdx.y;
  const float2* __restrict__ in = p.in[plane];
  const int mode = p.mode[plane];
  double* g = acp + ((size_t)((blockIdx.x & 3) * 21 + p.pi[plane])) * 41;
  float acc[41];
  #pragma unroll
  for (int k = 0; k < 41; k++) acc[k] = 0.f;
  const int tpr = H >> 5;
  const int nT = tpr * tpr;
  const int tid = threadIdx.x;
  const int tx4 = tid & 7, ty = tid >> 3;
  for (int ti = blockIdx.x; ti < nT; ti += gridDim.x) {
    __syncthreads();
    int by = (ti / tpr) << 5, bx = (ti % tpr) << 5;
    for (int ii = tid; ii < 1600; ii += 256) {
      int r = ii / 40, c = ii - r * 40;
      int gy = (by + r - 4) & (H - 1), gx = (bx + c - 4) & (H - 1);
      float2 v = in[(size_t)gy * H + gx];
      tile[r][c] = mode ? sqrtf(v.x * v.x + v.y * v.y) : v.x;
    }
    __syncthreads();
    float r9[8];
    #pragma unroll
    for (int j = 0; j < 8; j++) r9[j] = tile[ty + 4][4 * tx4 + 4 + j];
    float cen[4] = { r9[0], r9[1], r9[2], r9[3] };
    // dy = 0, dx = 0..4
    #pragma unroll
    for (int dx = 0; dx <= 4; dx++) {
      float s = 0.f;
      #pragma unroll
      for (int c = 0; c < 4; c++) s += cen[c] * r9[c + dx];
      acc[dx] += s;
    }
    // dy = 1..4, dx = -4..4
    #pragma unroll
    for (int dy = 1; dy <= 4; dy++) {
      float r[12];
      #pragma unroll
      for (int j = 0; j < 12; j++) r[j] = tile[ty + 4 + dy][4 * tx4 + j];
      #pragma unroll
      for (int dx = -4; dx <= 4; dx++) {
        float s = 0.f;
        #pragma unroll
        for (int c = 0; c < 4; c++) s += cen[c] * r[c + dx + 4];
        acc[5 + (dy - 1) * 9 + dx + 4] += s;
      }
    }
  }
  int wave = tid >> 6, lane = tid & 63;
  #pragma unroll
  for (int k = 0; k < 41; k++) {
    float x = acc[k];
    #pragma unroll
    for (int o = 32; o; o >>= 1) x += __shfl_down(x, o, 64);
    if (lane == 0) fred[wave * 41 + k] = x;
  }
  __syncthreads();
  for (int k = tid; k < 41; k += 256)
    atomicAdd(&g[k], (double)(fred[k] + fred[41 + k] + fred[82 + k] + fred[123 + k]));
}

// raw Grams of 4 band planes
__global__ __launch_bounds__(256, 4) void k_gram4(const float2* __restrict__ b0, const float2* __restrict__ b1,
                                                  const float2* __restrict__ b2, const float2* __restrict__ b3,
                                                  int n, double* c0out, double* crout) {
  __shared__ float red[128];
  float acc[32];
  #pragma unroll
  for (int k = 0; k < 32; k++) acc[k] = 0.f;
  for (int i = blockIdx.x * 256 + threadIdx.x; i < n; i += gridDim.x * 256) {
    float2 v0 = b0[i], v1 = b1[i], v2 = b2[i], v3 = b3[i];
    float a[4] = { sqrtf(v0.x * v0.x + v0.y * v0.y), sqrtf(v1.x * v1.x + v1.y * v1.y),
                   sqrtf(v2.x * v2.x + v2.y * v2.y), sqrtf(v3.x * v3.x + v3.y * v3.y) };
    float r[4] = { v0.x, v1.x, v2.x, v3.x };
    #pragma unroll
    for (int ii = 0; ii < 4; ii++)
      #pragma unroll
      for (int jj = 0; jj < 4; jj++) { acc[ii * 4 + jj] += a[ii] * a[jj]; acc[16 + ii * 4 + jj] += r[ii] * r[jj]; }
  }
  blk_reduce<32>(acc, red);
  int tid = threadIdx.x;
  if (tid < 16) atomicAdd(&c0out[tid], (double)red[tid]);
  else if (tid < 32) atomicAdd(&crout[tid - 16], (double)red[tid]);
}

__global__ __launch_bounds__(256, 4) void k_dots_rpar5(const float2* __restrict__ P,
                                                       const float2* __restrict__ b0, const float2* __restrict__ b1,
                                                       const float2* __restrict__ b2, const float2* __restrict__ b3,
                                                       double* crxB) {
  __shared__ float red[80];
  float acc[20];
  #pragma unroll
  for (int k = 0; k < 20; k++) acc[k] = 0.f;
  for (int i = blockIdx.x * 256 + threadIdx.x; i < 16384; i += gridDim.x * 256) {
    int y = i >> 7, x = i & 127;
    float tt[5];
    tt[0] = P[i].x;
    tt[1] = P[(y << 7) | ((x - 1) & 127)].x;
    tt[2] = P[(y << 7) | ((x + 1) & 127)].x;
    tt[3] = P[(((y - 1) & 127) << 7) | x].x;
    tt[4] = P[(((y + 1) & 127) << 7) | x].x;
    float r[4] = { b0[i].x, b1[i].x, b2[i].x, b3[i].x };
    #pragma unroll
    for (int a = 0; a < 4; a++)
      #pragma unroll
      for (int c = 0; c < 5; c++) acc[a * 5 + c] += r[a] * tt[c];
  }
  blk_reduce<20>(acc, red);
  int tid = threadIdx.x;
  if (tid < 20) atomicAdd(&crxB[(tid / 5) * 8 + (tid % 5)], (double)red[tid]);
}
__global__ __launch_bounds__(256, 4) void k_gram5(const float2* __restrict__ P, double* cr5) {
  __shared__ float red[100];
  float acc[25];
  #pragma unroll
  for (int k = 0; k < 25; k++) acc[k] = 0.f;
  for (int i = blockIdx.x * 256 + threadIdx.x; i < 16384; i += gridDim.x * 256) {
    int y = i >> 7, x = i & 127;
    float tt[5];
    tt[0] = P[i].x;
    tt[1] = P[(y << 7) | ((x - 1) & 127)].x;
    tt[2] = P[(y << 7) | ((x + 1) & 127)].x;
    tt[3] = P[(((y - 1) & 127) << 7) | x].x;
    tt[4] = P[(((y + 1) & 127) << 7) | x].x;
    #pragma unroll
    for (int a = 0; a < 5; a++)
      #pragma unroll
      for (int c = 0; c < 5; c++) acc[a * 5 + c] += tt[a] * tt[c];
  }
  blk_reduce<25>(acc, red);
  int tid = threadIdx.x;
  if (tid < 25) atomicAdd(&cr5[tid], (double)red[tid]);
}

// ================= finalize =================
__global__ __launch_bounds__(256) void k_finalize(const double* __restrict__ stg, const unsigned* __restrict__ stgu,
                                                  float* __restrict__ out) {
  int t = blockIdx.x * 256 + threadIdx.x;
  if (t >= 2456) return;
  const double N = 1048576.0;
  double m1 = stg[SG_PIX] / N, m2 = stg[SG_PIX + 1] / N;
  double vp = m2 - m1 * m1;
  if (t < 6) {
    double m3 = stg[SG_PIX + 2] / N, m4 = stg[SG_PIX + 3] / N;
    double cm3 = m3 - 3.0 * m1 * m2 + 2.0 * m1 * m1 * m1;
    double cm4 = m4 - 4.0 * m1 * m3 + 6.0 * m1 * m1 * m2 - 3.0 * m1 * m1 * m1 * m1;
    double r;
    if (t == 0) r = m1;
    else if (t == 1) r = vp * (N / (N - 1.0));
    else if (t == 2) r = cm3 / (vp * sqrt(vp));
    else if (t == 3) r = cm4 / (vp * vp);
    else if (t == 4) r = (double)funkey(stgu[1]);
    else r = (double)funkey(stgu[0]);
    out[t] = (float)r;
  } else if (t < 24) {
    int i = t - 6;
    double csz;
    if (i == 0) csz = 1048576.0;
    else if (i < 17) { int s = (i - 1) >> 2; double h = (double)(1024 >> s); csz = h * h; }
    else csz = 4096.0;
    out[t] = (float)(stg[SG_MAG + i] / csz);
  } else if (t < 1320) {
    int e = t - 24;
    int b = e & 3, s = (e >> 2) & 3, o = e >> 4;
    double h = (double)(1024 >> s); double csz = h * h;
    double m = stg[SG_MAG + 1 + 4 * s + b] / csz;
    int pi = s * 4 + b;
    int so = sidx(o);
    double sum = stg[SG_ACP + (0 * 21 + pi) * 41 + so] + stg[SG_ACP + (1 * 21 + pi) * 41 + so]
               + stg[SG_ACP + (2 * 21 + pi) * 41 + so] + stg[SG_ACP + (3 * 21 + pi) * 41 + so];
    out[t] = (float)(sum / csz - m * m);
  } else if (t < 1330) {
    int kurt = (t >= 1325);
    int s = t - (kurt ? 1325 : 1320);
    double h = (double)(1024 >> s); double csz = h * h;
    double vari = stg[SG_IMM + s * 3] / csz;
    double var0 = vp * (N / (N - 1.0));
    double v = vari > 1e-12 ? vari : 1e-12;
    double r;
    if (vari / var0 > 1e-6)
      r = kurt ? (stg[SG_IMM + s * 3 + 2] / csz) / (v * v) : (stg[SG_IMM + s * 3 + 1] / csz) / (v * sqrt(v));
    else
      r = kurt ? 3.0 : 0.0;
    out[t] = (float)r;
  } else if (t < 1735) {
    int e = t - 1330;
    int s = e % 5, o = e / 5;
    double h = (double)(1024 >> s);
    int pi = 16 + s;
    int so = sidx(o);
    double sum = stg[SG_ACP + (0 * 21 + pi) * 41 + so] + stg[SG_ACP + (1 * 21 + pi) * 41 + so]
               + stg[SG_ACP + (2 * 21 + pi) * 41 + so] + stg[SG_ACP + (3 * 21 + pi) * 41 + so];
    out[t] = (float)(sum / (h * h));
  } else if (t < 1815) {
    int e = t - 1735;
    int s = e % 5, o = e / 5;
    if (s < 4) {
      double h = (double)(1024 >> s); double csz = h * h;
      int i = o >> 2, j = o & 3;
      double mi = stg[SG_MAG + 1 + 4 * s + i] / csz;
      double mj = stg[SG_MAG + 1 + 4 * s + j] / csz;
      out[t] = (float)(stg[SG_C0 + s * 16 + o] / csz - mi * mj);
    } else out[t] = 0.0f;
  } else if (t < 1879) {
    int e = t - 1815;
    int s = e & 3, o = e >> 2;
    if (s < 3) {
      double h = (double)(1024 >> s); double csz = h * h;
      int c = o >> 2, b = o & 3;
      double mc = stg[SG_MAG + 1 + 4 * s + c] / csz;
      double pm = stg[SG_PMAG + 4 * s + b] / csz;
      out[t] = (float)(stg[SG_CX + s * 16 + o] / csz - mc * pm);
    } else out[t] = 0.0f;
  } else if (t < 2199) {
    int e = t - 1879;
    int s = e % 5, o = e / 5;
    int i = o >> 3, j = o & 7;
    float r = 0.0f;
    if (s < 4) { if (i < 4 && j < 4) { double h = (double)(1024 >> s); r = (float)(stg[SG_CR + s * 16 + i * 4 + j] / (h * h)); } }
    else { if (i < 5 && j < 5) r = (float)(stg[SG_CR5 + i * 5 + j] / 4096.0); }
    out[t] = r;
  } else if (t < 2455) {
    int e = t - 2199;
    int s = e & 3, o = e >> 2;
    int i = o >> 3, j = o & 7;
    float r = 0.0f;
    if (i < 4) {
      if (s < 3) { double h = (double)(1024 >> s); r = (float)(stg[SG_CRX + s * 32 + i * 8 + j] / (h * h)); }
      else if (j < 5) r = (float)(stg[SG_CRX + 96 + i * 8 + j] / 16384.0);
    }
    out[t] = r;
  } else {
    out[t] = (float)(stg[SG_HISQ] / N);
  }
}

// ================= host orchestration =================
static inline int rb(int n) { int b = (n + 255) / 256; return b > 256 ? 256 : b; }

struct Bufs {
  const float* img;
  float2* L[5];
  float2* Wg;
  double* stg; unsigned* stgu;
  float* out;
  char* w1;   // 40 MiB, 5 x 8MiB slots
  char* w2;   // 32 MiB, 4 x 8MiB slots
  char* l0raw;
};

template<int N>
static void scale_phase(const Bufs& B, int s, hipStream_t st) {
  constexpr int RPB = FftConst<N>::RPB;
  constexpr size_t PB = (size_t)N * N * 8;
  const int np = (N == 128) ? 6 : 5;
  // --- passA: {im, B0..3 [, Plo]} ---
  { PAp a{}; a.twg = B.Wg;
    a.in[0] = B.L[s]; a.mode[0] = MA_IM; a.aux[0] = 0;
    for (int b = 0; b < 4; b++) { a.in[1 + b] = B.L[s]; a.mode[1 + b] = MA_BAND; a.aux[1 + b] = b; }
    if (np == 6) { a.in[5] = B.L[4]; a.mode[5] = MA_EMBED_LO; a.aux[5] = 0; }
    for (int p = 0; p < np; p++) a.out[p] = (float2*)(B.w1 + p * PB);
    k_passA<N, true><<<dim3(N / RPB, np), 256, 0, st>>>(a); }
  // --- transpose ---
  float2* D[6];
  { TPp t{};
    for (int p = 0; p < np; p++) {
      D[p] = (N <= 512 || p < 4) ? (float2*)(B.w2 + p * PB) : (float2*)B.l0raw;
      t.src[p] = (const float2*)(B.w1 + p * PB); t.dst[p] = D[p];
    }
    k_transpose<<<dim3(N / 32, N / 32, np), 256, 0, st>>>(t, N); }
  // --- passB: spatial + fused stats ---
  { PBp bb{}; bb.twg = B.Wg;
    for (int p = 0; p < np; p++) { bb.in[p] = D[p]; bb.out[p] = (float2*)(B.w1 + p * PB); }
    bb.wmode[0] = WB_WRITE_IM; bb.red[0] = B.stg + SG_IMM + s * 3;
    for (int b = 0; b < 4; b++) { bb.wmode[1 + b] = WB_WRITE_MAG; bb.red[1 + b] = B.stg + SG_MAG + 1 + 4 * s + b; }
    if (np == 6) bb.wmode[5] = WB_WRITE;
    k_passB<N, true><<<dim3(N / RPB, np), 256, 0, st>>>(bb); }
  // --- autocorr (im + 4 bands), partitioned symmetric raw sums ---
  { ACp c{};
    c.in[0] = (const float2*)(B.w1); c.pi[0] = 16 + s; c.mode[0] = 0;
    for (int b = 0; b < 4; b++) { c.in[1 + b] = (const float2*)(B.w1 + (1 + b) * PB); c.pi[1 + b] = s * 4 + b; c.mode[1 + b] = 1; }
    int nT = (N / 32) * (N / 32);
    k_autocorr<<<dim3(nT > 256 ? 256 : nT, 5), 256, 0, st>>>(c, N, B.stg + SG_ACP); }
  // --- raw gram ---
  k_gram4<<<rb(N * N), 256, 0, st>>>((const float2*)(B.w1 + PB), (const float2*)(B.w1 + 2 * PB),
                                     (const float2*)(B.w1 + 3 * PB), (const float2*)(B.w1 + 4 * PB),
                                     N * N, B.stg + SG_C0 + s * 16, B.stg + SG_CR + s * 16);
  if (s < 3) {
    // --- parents: one 4-plane passA, then 2x (transpose + pdots passB) ---
    { PAp a{}; a.twg = B.Wg;
      for (int b = 0; b < 4; b++) { a.in[b] = B.L[s + 1]; a.mode[b] = MA_EMBED_BAND; a.aux[b] = b; a.out[b] = (float2*)(B.w2 + b * PB); }
      k_passA<N, true><<<dim3(N / RPB, 4), 256, 0, st>>>(a); }
    char* td0; char* td1;
    if (N == 1024) { td0 = B.l0raw; td1 = B.w1; }            // L0 and im-slot free by now
    else { td0 = B.w2 + 4 * PB; td1 = B.w2 + 5 * PB; }
    for (int pr = 0; pr < 2; pr++) {
      { TPp t{};
        t.src[0] = (const float2*)(B.w2 + (2 * pr) * PB); t.dst[0] = (float2*)td0;
        t.src[1] = (const float2*)(B.w2 + (2 * pr + 1) * PB); t.dst[1] = (float2*)td1;
        k_transpose<<<dim3(N / 32, N / 32, 2), 256, 0, st>>>(t, N); }
      { PBp bb{}; bb.twg = B.Wg;
        bb.in[0] = (const float2*)td0; bb.in[1] = (const float2*)td1;
        for (int k = 0; k < 2; k++) { int b = pr * 2 + k; bb.wmode[k] = WB_PDOTS; bb.aux[k] = b; bb.red[k] = B.stg + SG_PMAG + 4 * s + b; }
        for (int cc = 0; cc < 4; cc++) bb.Bp[cc] = (const float2*)(B.w1 + (1 + cc) * PB);
        bb.cx = B.stg + SG_CX + s * 16; bb.crx = B.stg + SG_CRX + s * 32;
        k_passB<N, true><<<dim3(N / RPB, 2), 256, 0, st>>>(bb); }
    }
  } else {
    k_dots_rpar5<<<64, 256, 0, st>>>((const float2*)(B.w1 + 5 * PB),
                                     (const float2*)(B.w1 + PB), (const float2*)(B.w1 + 2 * PB),
                                     (const float2*)(B.w1 + 3 * PB), (const float2*)(B.w1 + 4 * PB),
                                     B.stg + SG_CRX + 96);
    k_gram5<<<64, 256, 0, st>>>((const float2*)(B.w1 + 5 * PB), B.stg + SG_CR5);
  }
}

extern "C" void kernel_launch(void* const* d_in, const int* in_sizes, int n_in,
                              void* d_out, int out_size, void* d_ws, size_t ws_size,
                              hipStream_t stream) {
  (void)in_sizes; (void)n_in; (void)out_size;
  if (ws_size < 87031808ull) return;   // 83 MiB
  char* w = (char*)d_ws;
  Bufs B;
  B.img = (const float*)d_in[0];
  B.out = (float*)d_out;
  B.L[0] = (float2*)(w + 0ull);
  B.L[1] = (float2*)(w + 8388608ull);
  B.L[2] = (float2*)(w + 10485760ull);
  B.L[3] = (float2*)(w + 11010048ull);
  B.L[4] = (float2*)(w + 11141120ull);
  B.Wg   = (float2*)(w + 11173888ull);
  B.stg  = (double*)(w + 11177984ull);
  B.stgu = (unsigned*)(B.stg + NSTG);
  B.w1   = w + 11534336ull;            // 40 MiB
  B.w2   = w + 53477376ull;            // 32 MiB
  B.l0raw = w;                          // L0 region, reused once free
  hipStream_t st = stream;
  double* stg = B.stg;
  constexpr size_t PB8 = 8388608ull;

  k_init<<<16, 256, 0, st>>>(stg, B.stgu, B.Wg);

  // forward fft2 with fused pixel raw moments: img -> rows-FFT (w1 s0), transpose, masked spectra
  k_fwdA<<<1024, 256, 0, st>>>(B.img, (float2*)(B.w1), B.Wg, stg, B.stgu);
  { TPp t{}; t.src[0] = (const float2*)(B.w1); t.dst[0] = (float2*)(B.w2);
    k_transpose<<<dim3(32, 32, 1), 256, 0, st>>>(t, 1024); }
  { PBp bb{}; bb.twg = B.Wg; bb.in[0] = (const float2*)(B.w2); bb.wmode[0] = WB_FWD_MASK;
    bb.out[0] = (float2*)(B.w1 + PB8); bb.out2 = B.L[0];
    k_passB<1024, false><<<dim3(1024, 1), 256, 0, st>>>(bb); }

  // hi residual: ifft2 of hi-spec, reduce-only (sum|re|, re^2)
  { PAp a{}; a.twg = B.Wg; a.in[0] = (const float2*)(B.w1 + PB8); a.mode[0] = MA_C2; a.aux[0] = 0;
    a.out[0] = (float2*)(B.w1);
    k_passA<1024, true><<<dim3(1024, 1), 256, 0, st>>>(a); }
  { TPp t{}; t.src[0] = (const float2*)(B.w1); t.dst[0] = (float2*)(B.w2);
    k_transpose<<<dim3(32, 32, 1), 256, 0, st>>>(t, 1024); }
  { PBp bb{}; bb.twg = B.Wg; bb.in[0] = (const float2*)(B.w2); bb.wmode[0] = WB_RED_HI;
    bb.red[0] = stg + SG_MAG; bb.red2 = stg + SG_HISQ;
    k_passB<1024, true><<<dim3(1024, 1), 256, 0, st>>>(bb); }

  // lowpass chain, single dispatch
  k_ldown<<<1360, 256, 0, st>>>(B.L[0], B.L[1], B.L[2], B.L[3], B.L[4]);

  // size-64 batch: {lo-resid (plain ifft of L4), imF4 = L4*lo0}
  {
    constexpr size_t PB = 64ull * 64ull * 8ull;
    constexpr int RPB = FftConst<64>::RPB;
    { PAp a{}; a.twg = B.Wg;
      a.in[0] = B.L[4]; a.mode[0] = MA_C2; a.aux[0] = 0; a.out[0] = (float2*)(B.w1);
      a.in[1] = B.L[4]; a.mode[1] = MA_IMF4; a.aux[1] = 0; a.out[1] = (float2*)(B.w1 + PB);
      k_passA<64, true><<<dim3(64 / RPB, 2), 256, 0, st>>>(a); }
    { TPp t{};
      t.src[0] = (const float2*)(B.w1); t.dst[0] = (float2*)(B.w2);
      t.src[1] = (const float2*)(B.w1 + PB); t.dst[1] = (float2*)(B.w2 + PB);
      k_transpose<<<dim3(2, 2, 2), 256, 0, st>>>(t, 64); }
    { PBp bb{}; bb.twg = B.Wg;
      bb.in[0] = (const float2*)(B.w2); bb.wmode[0] = WB_RED_ABSRE; bb.red[0] = stg + SG_MAG + 17;
      bb.in[1] = (const float2*)(B.w2 + PB); bb.wmode[1] = WB_WRITE_IM; bb.red[1] = stg + SG_IMM + 12;
      bb.out[1] = (float2*)(B.w1 + PB);
      k_passB<64, true><<<dim3(64 / RPB, 2), 256, 0, st>>>(bb); }
    { ACp c{}; c.in[0] = (const float2*)(B.w1 + PB); c.pi[0] = 20; c.mode[0] = 0;
      k_autocorr<<<dim3(4, 1), 256, 0, st>>>(c, 64, stg + SG_ACP); }
  }

  // per-scale batches
  scale_phase<128>(B, 3, st);
  scale_phase<256>(B, 2, st);
  scale_phase<512>(B, 1, st);
  scale_phase<1024>(B, 0, st);

  k_finalize<<<10, 256, 0, st>>>(stg, B.stgu, B.out);
}

// Round 8
// 688.207 us; speedup vs baseline: 1.3843x; 1.1885x over previous
//
#include <hip/hip_runtime.h>
#include <math.h>

#define PI_F      3.14159265358979323846f
#define TWOPI_F   6.28318530717958647692f
#define HALFPI_F  1.57079632679489661923f
#define ANG_F     0.8944271909999159f

// ---- staging layout (doubles); every scalar sink is 16-way partitioned ----
#define NP       16
#define SG_PIX   0                       // [4][NP] raw moments
#define SG_MAG   (SG_PIX + 4 * NP)       // [18][NP]
#define SG_HISQ  (SG_MAG + 18 * NP)      // [NP]
#define SG_PMAG  (SG_HISQ + NP)          // [12][NP]
#define SG_IMM   (SG_PMAG + 12 * NP)     // [15][NP]
#define SG_ACP   (SG_IMM + 15 * NP)      // [4 part][21 planes][41]
#define SG_C0    (SG_ACP + 4 * 21 * 41)  // [4][16][NP]
#define SG_CR    (SG_C0 + 4 * 16 * NP)   // [4][16][NP]
#define SG_CX    (SG_CR + 4 * 16 * NP)   // [3][16][NP]
#define SG_CRX   (SG_CX + 3 * 16 * NP)   // [4][32][NP]
#define SG_CR5   (SG_CRX + 4 * 32 * NP)  // [25][NP]
#define NSTG     (SG_CR5 + 25 * NP)

enum { MA_C2 = 0, MA_REAL, MA_BAND, MA_EMBED_BAND, MA_EMBED_LO, MA_IMF4, MA_IM };
enum { WB_WRITE = 0, WB_WRITE_MAG, WB_WRITE_IM, WB_RED_HI, WB_RED_ABSRE, WB_FWD_MASK, WB_PDOTS };

__device__ __forceinline__ int sfreq(int k, int H) { return (k < (H >> 1)) ? k : k - H; }
__device__ __forceinline__ int skx(int i) { return i + (i >> 4); }   // LDS bank skew

__device__ __forceinline__ float d_lograd(int fy, int fx, int H) {
  float cy = (float)fy * (2.0f / (float)H);
  float cx = (float)fx * (2.0f / (float)H);
  float rad = sqrtf(cx * cx + cy * cy);
  if (fy == 0 && fx == 0) rad = 2.0f / (float)H;   // reference DC hack
  return log2f(rad);
}
__device__ __forceinline__ float d_angle(int fy, int fx, int H) {
  return atan2f((float)fy * (2.0f / (float)H), (float)fx * (2.0f / (float)H));
}
__device__ __forceinline__ float d_rc(float x) {
  float c = fminf(fmaxf(-x, 0.0f), 1.0f);
  float t = cosf(0.5f * PI_F * c);
  return t * t;
}
__device__ __forceinline__ float d_alfa(float ang, int b) {
  float bc = (b == 0) ? 0.0f : (b == 1) ? 0.78539816339744830962f
           : (b == 2) ? 1.57079632679489661923f : 2.35619449019234492885f;
  float t = (PI_F + ang) - bc;
  float m = fmodf(t, TWOPI_F);
  if (m < 0.0f) m += TWOPI_F;
  return m - PI_F;
}
__device__ __forceinline__ float d_cos3(float a) { float c = cosf(a); return ANG_F * c * c * c; }
__device__ __forceinline__ float d_amaskC(float ang, int b) {
  float alfa = d_alfa(ang, b);
  float A = d_cos3(alfa);
  return (fabsf(alfa) < HALFPI_F) ? 2.0f * A : 0.0f;
}
__device__ __forceinline__ float d_lo(int fy, int fx, int H) {
  return sqrtf(fmaxf(1.0f - d_rc(d_lograd(fy, fx, H)), 0.0f));
}
// recon mask at native size H
__device__ __forceinline__ float d_mm(int fy, int fx, int H) {
  float lr = d_lograd(fy, fx, H);
  float hm2 = d_rc(lr + 1.0f);
  float lo0 = sqrtf(fmaxf(1.0f - d_rc(lr), 0.0f));
  float ang1 = d_angle(fy, fx, H);
  int gfy = (fy == -(H >> 1)) ? fy : -fy;
  int gfx = (fx == -(H >> 1)) ? fx : -fx;
  float ang2 = d_angle(gfy, gfx, H);
  float msum = 0.0f;
  #pragma unroll
  for (int b4 = 0; b4 < 4; b4++) {
    float a1 = d_alfa(ang1, b4), a2 = d_alfa(ang2, b4);
    float A1 = d_cos3(a1), A2 = d_cos3(a2);
    float T1 = (fabsf(a1) < HALFPI_F) ? A1 : 0.0f;
    float T2 = (fabsf(a2) < HALFPI_F) ? A2 : 0.0f;
    msum += A1 * (T1 - T2);
  }
  return lo0 * hm2 * msum;
}
// accumulated im-chain mask at scale with native size N (N>=128)
template<int N>
__device__ __forceinline__ float d_G(int fy, int fx) {
  float g = d_mm(fy, fx, N);
  float chain = 1.0f;
  #pragma unroll
  for (int Nj = (N >> 1); Nj >= 64; Nj >>= 1) {
    int h = Nj >> 1;
    if (fy < -h || fy >= h || fx < -h || fx >= h) break;
    chain *= d_lo(fy, fx, Nj);
    if (Nj > 64) g += chain * d_mm(fy, fx, Nj);
    else g += chain * d_lo(fy, fx, 64);
  }
  if (fy == 0 && fx == 0) g = 0.0f;
  return g;
}
__device__ __forceinline__ unsigned fkey(float f) {
  unsigned u = __float_as_uint(f);
  return (u & 0x80000000u) ? ~u : (u | 0x80000000u);
}
__device__ __forceinline__ float funkey(unsigned k) {
  return (k & 0x80000000u) ? __uint_as_float(k & 0x7FFFFFFFu) : __uint_as_float(~k);
}
// map full 9x9 offset index (0..80) to symmetric 41-index
__device__ __forceinline__ int sidx(int o) {
  int dy = o / 9 - 4, dx = o - (o / 9) * 9 - 4;
  if (dy < 0 || (dy == 0 && dx < 0)) { dy = -dy; dx = -dx; }
  return (dy == 0) ? dx : 5 + (dy - 1) * 9 + dx + 4;
}

template<int K>
__device__ __forceinline__ void blk_reduce(float* v, float* red) {
  int tid = threadIdx.x, wave = tid >> 6, lane = tid & 63;
  #pragma unroll
  for (int k = 0; k < K; k++) {
    float x = v[k];
    #pragma unroll
    for (int o = 32; o; o >>= 1) x += __shfl_down(x, o, 64);
    if (lane == 0) red[wave * K + k] = x;
  }
  __syncthreads();
  if (tid < K) red[tid] = red[tid] + red[K + tid] + red[2 * K + tid] + red[3 * K + tid];
}

// ================= FFT core (Stockham, radix-4 with leading radix-2) =================
template<int N> struct FftConst {
  static constexpr int L2N = (N == 64) ? 6 : (N == 128) ? 7 : (N == 256) ? 8 : (N == 512) ? 9 : 10;
  static constexpr int TPR = (N / 4 >= 256) ? 256 : ((N / 4 < 16) ? 16 : N / 4);
  static constexpr int RPB = 256 / TPR;
  static constexpr int BUF = N + (N >> 4);
};

template<int N, bool INV>
__device__ __forceinline__ float2* fft_core(float2* A, float2* B, const float2* tw, int tr) {
  constexpr int TPR = FftConst<N>::TPR;
  constexpr int L2N = FftConst<N>::L2N;
  float2* src = A; float2* dst = B;
  if constexpr (L2N & 1) {
    for (int t = tr; t < (N >> 1); t += TPR) {
      float2 w = tw[t];
      float cv = w.x, sv = INV ? w.y : -w.y;
      float2 a = src[skx(t)];
      float2 b = src[skx(t + (N >> 1))];
      float dx = a.x - b.x, dy = a.y - b.y;
      dst[skx(2 * t)] = make_float2(a.x + b.x, a.y + b.y);
      dst[skx(2 * t + 1)] = make_float2(dx * cv - dy * sv, dx * sv + dy * cv);
    }
    __syncthreads();
    float2* tmp = src; src = dst; dst = tmp;
  }
  #pragma unroll
  for (int st = (L2N & 1); st < L2N; st += 2) {
    for (int t = tr; t < (N >> 2); t += TPR) {
      int p = t >> st;
      int q = t & ((1 << st) - 1);
      int i0 = q + (p << st);
      float2 x0 = src[skx(i0)];
      float2 x1 = src[skx(i0 + (N >> 2))];
      float2 x2 = src[skx(i0 + (N >> 1))];
      float2 x3 = src[skx(i0 + 3 * (N >> 2))];
      float2 w = tw[p << st];
      float c1 = w.x, s1 = INV ? w.y : -w.y;
      float c2 = c1 * c1 - s1 * s1, s2 = 2.f * c1 * s1;
      float c3 = c2 * c1 - s2 * s1, s3 = c2 * s1 + s2 * c1;
      float e0x = x0.x + x2.x, e0y = x0.y + x2.y;
      float e1x = x0.x - x2.x, e1y = x0.y - x2.y;
      float o0x = x1.x + x3.x, o0y = x1.y + x3.y;
      float d1x = x1.x - x3.x, d1y = x1.y - x3.y;
      float o1x, o1y;
      if constexpr (INV) { o1x = -d1y; o1y = d1x; }
      else               { o1x = d1y;  o1y = -d1x; }
      float t1x = e1x + o1x, t1y = e1y + o1y;
      float t2x = e0x - o0x, t2y = e0y - o0y;
      float t3x = e1x - o1x, t3y = e1y - o1y;
      int o = q + (p << (st + 2));
      int s = 1 << st;
      dst[skx(o)]         = make_float2(e0x + o0x, e0y + o0y);
      dst[skx(o + s)]     = make_float2(t1x * c1 - t1y * s1, t1x * s1 + t1y * c1);
      dst[skx(o + 2 * s)] = make_float2(t2x * c2 - t2y * s2, t2x * s2 + t2y * c2);
      dst[skx(o + 3 * s)] = make_float2(t3x * c3 - t3y * s3, t3x * s3 + t3y * c3);
    }
    __syncthreads();
    float2* tmp = src; src = dst; dst = tmp;
  }
  return src;
}

struct PAp {
  const float2* in[6];
  float2* out[6];
  const float2* twg;
  int mode[6];
  int aux[6];
};
struct PBp {
  const float2* in[6];
  float2* out[6];
  float2* out2;
  const float2* Bp[4];
  double* red[6];
  double* red2;
  double* cx;
  double* crx;
  const float2* twg;
  int wmode[6];
  int aux[6];
};
struct TPp { const float2* src[6]; float2* dst[6]; };
struct ACp { const float2* in[5]; int pi[5]; int mode[5]; };

template<int N, int MODE>
__device__ __forceinline__ float2 loadA(const float2* in, int row, int i, int b) {
  if constexpr (MODE == MA_C2) {
    return in[(size_t)row * N + i];
  } else if constexpr (MODE == MA_REAL) {
    const float* f = (const float*)in;
    return make_float2(f[(size_t)row * N + i], 0.0f);
  } else if constexpr (MODE == MA_BAND) {
    int fy = sfreq(i, N), fx = sfreq(row, N);
    float m = sqrtf(d_rc(d_lograd(fy, fx, N) + 1.0f)) * d_amaskC(d_angle(fy, fx, N), b);
    float2 l = in[(size_t)row * N + i];
    return make_float2(-l.y * m, l.x * m);
  } else if constexpr (MODE == MA_EMBED_BAND) {
    int fy = sfreq(i, N), fx = sfreq(row, N);
    int q = N >> 2, h2 = N >> 1;
    if (fy < -q || fy >= q || fx < -q || fx >= q) return make_float2(0.f, 0.f);
    int U = fx >= 0 ? fx : fx + h2, V = fy >= 0 ? fy : fy + h2;
    float m = sqrtf(d_rc(d_lograd(fy, fx, h2) + 1.0f)) * d_amaskC(d_angle(fy, fx, h2), b);
    float2 l = in[(size_t)U * h2 + V];
    return make_float2(-l.y * m, l.x * m);
  } else if constexpr (MODE == MA_EMBED_LO) {
    int fy = sfreq(i, N), fx = sfreq(row, N);
    int q = N >> 2, h2 = N >> 1;
    if (fy < -q || fy >= q || fx < -q || fx >= q) return make_float2(0.f, 0.f);
    int U = fx >= 0 ? fx : fx + h2, V = fy >= 0 ? fy : fy + h2;
    return in[(size_t)U * h2 + V];
  } else if constexpr (MODE == MA_IMF4) {
    int fy = sfreq(i, N), fx = sfreq(row, N);
    float lo = d_lo(fy, fx, N);
    float2 v = in[(size_t)row * N + i];
    return make_float2(v.x * lo, v.y * lo);
  } else {  // MA_IM
    int fy = sfreq(i, N), fx = sfreq(row, N);
    float g = d_G<N>(fy, fx);
    float2 l = in[(size_t)row * N + i];
    return make_float2(l.x * g, l.y * g);
  }
}

// pass A: fused load op -> row FFT -> write
template<int N, bool INV>
__global__ __launch_bounds__(256) void k_passA(PAp p) {
  using FC = FftConst<N>;
  __shared__ float2 shA[FC::RPB][FC::BUF];
  __shared__ float2 shB[FC::RPB][FC::BUF];
  __shared__ float2 tw[N / 2];
  int tid = threadIdx.x;
  for (int k = tid; k < N / 2; k += 256) tw[k] = p.twg[k << (10 - FC::L2N)];
  int rl = tid / FC::TPR;
  int tr = tid % FC::TPR;
  int row = blockIdx.x * FC::RPB + rl;
  int plane = blockIdx.y;
  const float2* in = p.in[plane];
  int mode = p.mode[plane];
  int b = p.aux[plane];
  float2* A = shA[rl];
  switch (mode) {
    case MA_C2:         for (int i = tr; i < N; i += FC::TPR) A[skx(i)] = loadA<N, MA_C2>(in, row, i, b); break;
    case MA_REAL:       for (int i = tr; i < N; i += FC::TPR) A[skx(i)] = loadA<N, MA_REAL>(in, row, i, b); break;
    case MA_BAND:       for (int i = tr; i < N; i += FC::TPR) A[skx(i)] = loadA<N, MA_BAND>(in, row, i, b); break;
    case MA_EMBED_BAND: for (int i = tr; i < N; i += FC::TPR) A[skx(i)] = loadA<N, MA_EMBED_BAND>(in, row, i, b); break;
    case MA_EMBED_LO:   for (int i = tr; i < N; i += FC::TPR) A[skx(i)] = loadA<N, MA_EMBED_LO>(in, row, i, b); break;
    case MA_IMF4:       for (int i = tr; i < N; i += FC::TPR) A[skx(i)] = loadA<N, MA_IMF4>(in, row, i, b); break;
    default:            for (int i = tr; i < N; i += FC::TPR) A[skx(i)] = loadA<N, MA_IM>(in, row, i, b); break;
  }
  __syncthreads();
  float2* res = fft_core<N, INV>(A, shB[rl], tw, tr);
  constexpr float sc = INV ? 1.0f / (float)N : 1.0f;
  float2* o = p.out[plane] + (size_t)row * N;
  for (int i = tr; i < N; i += FC::TPR) {
    float2 v = res[skx(i)];
    o[i] = make_float2(v.x * sc, v.y * sc);
  }
}

// forward passA over the raw image with fused raw pixel moments + min/max (partitioned sinks)
__global__ __launch_bounds__(256) void k_fwdA(const float* __restrict__ img, float2* __restrict__ out,
                                              const float2* __restrict__ twg, double* stg, unsigned* stgu) {
  using FC = FftConst<1024>;
  __shared__ float2 shA[FC::BUF];
  __shared__ float2 shB[FC::BUF];
  __shared__ float2 tw[512];
  __shared__ float red[16];
  int tid = threadIdx.x;
  int part = blockIdx.x & (NP - 1);
  for (int k = tid; k < 512; k += 256) tw[k] = twg[k];
  int row = blockIdx.x;
  float s1 = 0.f, s2 = 0.f, s3 = 0.f, s4 = 0.f;
  float mn = 3.402823466e38f, mx = -3.402823466e38f;
  for (int i = tid; i < 1024; i += 256) {
    float x = img[(size_t)row * 1024 + i];
    shA[skx(i)] = make_float2(x, 0.f);
    float x2 = x * x;
    s1 += x; s2 += x2; s3 += x2 * x; s4 += x2 * x2;
    mn = fminf(mn, x); mx = fmaxf(mx, x);
  }
  float accv[4] = {s1, s2, s3, s4};
  blk_reduce<4>(accv, red);
  if (tid < 4) atomicAdd(&stg[SG_PIX + tid * NP + part], (double)red[tid]);
  #pragma unroll
  for (int o = 32; o; o >>= 1) { mn = fminf(mn, __shfl_down(mn, o, 64)); mx = fmaxf(mx, __shfl_down(mx, o, 64)); }
  if ((tid & 63) == 0) { atomicMin(&stgu[NP + part], fkey(mn)); atomicMax(&stgu[part], fkey(mx)); }
  float2* res = fft_core<1024, false>(shA, shB, tw, tid);
  float2* o = out + (size_t)row * 1024;
  for (int i = tid; i < 1024; i += 256) o[i] = res[skx(i)];
}

// pass B: plain load -> row FFT -> write / fused reductions (partitioned sinks)
template<int N, bool INV>
__global__ __launch_bounds__(256) void k_passB(PBp p) {
  using FC = FftConst<N>;
  __shared__ float2 shA[FC::RPB][FC::BUF];
  __shared__ float2 shB[FC::RPB][FC::BUF];
  __shared__ float2 tw[N / 2];
  __shared__ float red[52];
  int tid = threadIdx.x;
  int part = blockIdx.x & (NP - 1);
  for (int k = tid; k < N / 2; k += 256) tw[k] = p.twg[k << (10 - FC::L2N)];
  int rl = tid / FC::TPR;
  int tr = tid % FC::TPR;
  int row = blockIdx.x * FC::RPB + rl;
  int plane = blockIdx.y;
  const float2* in = p.in[plane] + (size_t)row * N;
  float2* A = shA[rl];
  for (int i = tr; i < N; i += FC::TPR) A[skx(i)] = in[i];
  __syncthreads();
  float2* res = fft_core<N, INV>(A, shB[rl], tw, tr);
  constexpr float sc = INV ? 1.0f / (float)N : 1.0f;
  int wmode = p.wmode[plane];
  if (wmode == WB_WRITE || wmode == WB_WRITE_MAG || wmode == WB_WRITE_IM) {
    float2* o = p.out[plane] + (size_t)row * N;
    float a0 = 0.f, a1 = 0.f, a2 = 0.f;
    for (int i = tr; i < N; i += FC::TPR) {
      float2 v = res[skx(i)];
      v.x *= sc; v.y *= sc;
      o[i] = v;
      if (wmode == WB_WRITE_MAG) a0 += sqrtf(v.x * v.x + v.y * v.y);
      else if (wmode == WB_WRITE_IM) { float v2 = v.x * v.x; a0 += v2; a1 += v2 * v.x; a2 += v2 * v2; }
    }
    if (wmode == WB_WRITE_MAG) {
      float acc[1] = {a0}; blk_reduce<1>(acc, red);
      if (tid == 0) atomicAdd(p.red[plane] + part, (double)red[0]);
    } else if (wmode == WB_WRITE_IM) {
      float acc[3] = {a0, a1, a2}; blk_reduce<3>(acc, red);
      if (tid < 3) atomicAdd(&p.red[plane][tid * NP + part], (double)red[tid]);
    }
  } else if (wmode == WB_RED_HI) {
    float a0 = 0.f, a1 = 0.f;
    for (int i = tr; i < N; i += FC::TPR) {
      float v = res[skx(i)].x * sc;
      a0 += fabsf(v); a1 += v * v;
    }
    float acc[2] = {a0, a1}; blk_reduce<2>(acc, red);
    if (tid == 0) atomicAdd(p.red[plane] + part, (double)red[0]);
    if (tid == 1) atomicAdd(p.red2 + part, (double)red[1]);
  } else if (wmode == WB_RED_ABSRE) {
    float a0 = 0.f;
    for (int i = tr; i < N; i += FC::TPR) a0 += fabsf(res[skx(i)].x * sc);
    float acc[1] = {a0}; blk_reduce<1>(acc, red);
    if (tid == 0) atomicAdd(p.red[plane] + part, (double)red[0]);
  } else if (wmode == WB_FWD_MASK) {
    float2* o1 = p.out[plane] + (size_t)row * N;
    float2* o2 = p.out2 + (size_t)row * N;
    int fx = sfreq(row, N);
    for (int i = tr; i < N; i += FC::TPR) {
      float2 v = res[skx(i)];
      int fy = sfreq(i, N);
      float rcv = d_rc(d_lograd(fy, fx, N));
      float hi = sqrtf(rcv), lo = sqrtf(fmaxf(1.0f - rcv, 0.0f));
      o1[i] = make_float2(v.x * hi, v.y * hi);
      o2[i] = make_float2(v.x * lo, v.y * lo);
    }
  } else {  // WB_PDOTS
    int b = p.aux[plane];
    float acc[13];
    #pragma unroll
    for (int k = 0; k < 13; k++) acc[k] = 0.f;
    for (int i = tr; i < N; i += FC::TPR) {
      float2 v = res[skx(i)];
      v.x *= sc; v.y *= sc;
      float mag = sqrtf(v.x * v.x + v.y * v.y);
      float rr = 0.f, ri = 0.f;
      if (mag > 0.f) { rr = (v.y * v.y - v.x * v.x) / mag; ri = 2.f * v.x * v.y / mag; }
      size_t idx = (size_t)row * N + i;
      #pragma unroll
      for (int c = 0; c < 4; c++) {
        float2 bv = p.Bp[c][idx];
        float am = sqrtf(bv.x * bv.x + bv.y * bv.y);
        acc[c] += am * mag;
        acc[4 + c] += bv.x * rr;
        acc[8 + c] += bv.x * ri;
      }
      acc[12] += mag;
    }
    blk_reduce<13>(acc, red);
    if (tid < 4) atomicAdd(&p.cx[(tid * 4 + b) * NP + part], (double)red[tid]);
    else if (tid < 8) atomicAdd(&p.crx[((tid - 4) * 8 + b) * NP + part], (double)red[tid]);
    else if (tid < 12) atomicAdd(&p.crx[((tid - 8) * 8 + 4 + b) * NP + part], (double)red[tid]);
    else if (tid == 12) atomicAdd(p.red[plane] + part, (double)red[12]);
  }
}

__global__ __launch_bounds__(256) void k_transpose(TPp p, int N) {
  __shared__ float2 tile[32][33];
  int z = blockIdx.z;
  const float2* in = p.src[z];
  float2* out = p.dst[z];
  int bx = blockIdx.x << 5, by = blockIdx.y << 5;
  int tx = threadIdx.x & 31, ty = threadIdx.x >> 5;
  for (int r = ty; r < 32; r += 8) tile[r][tx] = in[(size_t)(by + r) * N + bx + tx];
  __syncthreads();
  for (int r = ty; r < 32; r += 8) out[(size_t)(bx + r) * N + by + tx] = tile[tx][r];
}

// all 4 lowpass levels from L0 in one dispatch (cumulative masks)
__global__ __launch_bounds__(256) void k_ldown(const float2* __restrict__ L0,
                                               float2* __restrict__ L1, float2* __restrict__ L2,
                                               float2* __restrict__ L3, float2* __restrict__ L4) {
  int idx = blockIdx.x * 256 + threadIdx.x;
  int s, N, i;
  float2* dst;
  if (idx < 262144)      { s = 1; N = 512; i = idx;          dst = L1; }
  else if (idx < 327680) { s = 2; N = 256; i = idx - 262144; dst = L2; }
  else if (idx < 344064) { s = 3; N = 128; i = idx - 327680; dst = L3; }
  else if (idx < 348160) { s = 4; N = 64;  i = idx - 344064; dst = L4; }
  else return;
  int fy = sfreq(i / N, N), fx = sfreq(i % N, N);
  float m = 1.0f;
  for (int j = 1; j <= s; j++) m *= d_lo(fy, fx, 1024 >> j);
  int by = fy >= 0 ? fy : fy + 1024;
  int bx = fx >= 0 ? fx : fx + 1024;
  float2 v = L0[(size_t)by * 1024 + bx];
  if (s == 4 && i == 0) { dst[0] = make_float2(0.f, 0.f); return; }
  dst[i] = make_float2(v.x * m, v.y * m);
}

// ================= reductions / stats =================
__global__ __launch_bounds__(256) void k_init(double* stg, unsigned* stgu, float2* Wg) {
  int i = blockIdx.x * 256 + threadIdx.x;
  if (i < NSTG) stg[i] = 0.0;
  if (i < NP) stgu[i] = 0u;                       // max keys
  else if (i < 2 * NP) stgu[i] = 0xFFFFFFFFu;     // min keys
  if (i < 512) {
    float a = TWOPI_F * (float)i * (1.0f / 1024.0f);
    float sv, cv; sincosf(a, &sv, &cv);
    Wg[i] = make_float2(cv, sv);
  }
}

// central 9x9 circular autocorrelation, RAW sums, symmetry-halved (41 offsets).
__global__ __launch_bounds__(256, 3) void k_autocorr(ACp p, int H, double* acp) {
  __shared__ float tile[40][41];
  __shared__ float fred[4 * 41];
  const int plane = blockIdx.y;
  const float2* __restrict__ in = p.in[plane];
  const int mode = p.mode[plane];
  double* g = acp + ((size_t)((blockIdx.x & 3) * 21 + p.pi[plane])) * 41;
  float acc[41];
  #pragma unroll
  for (int k = 0; k < 41; k++) acc[k] = 0.f;
  const int tpr = H >> 5;
  const int nT = tpr * tpr;
  const int tid = threadIdx.x;
  const int tx4 = tid & 7, ty = tid >> 3;
  for (int ti = blockIdx.x; ti < nT; ti += gridDim.x) {
    __syncthreads();
    int by = (ti / tpr) << 5, bx = (ti % tpr) << 5;
    for (int ii = tid; ii < 1600; ii += 256) {
      int r = ii / 40, c = ii - r * 40;
      int gy = (by + r - 4) & (H - 1), gx = (bx + c - 4) & (H - 1);
      float2 v = in[(size_t)gy * H + gx];
      tile[r][c] = mode ? sqrtf(v.x * v.x + v.y * v.y) : v.x;
    }
    __syncthreads();
    float r9[8];
    #pragma unroll
    for (int j = 0; j < 8; j++) r9[j] = tile[ty + 4][4 * tx4 + 4 + j];
    float cen[4] = { r9[0], r9[1], r9[2], r9[3] };
    #pragma unroll
    for (int dx = 0; dx <= 4; dx++) {
      float s = 0.f;
      #pragma unroll
      for (int c = 0; c < 4; c++) s += cen[c] * r9[c + dx];
      acc[dx] += s;
    }
    #pragma unroll
    for (int dy = 1; dy <= 4; dy++) {
      float r[12];
      #pragma unroll
      for (int j = 0; j < 12; j++) r[j] = tile[ty + 4 + dy][4 * tx4 + j];
      #pragma unroll
      for (int dx = -4; dx <= 4; dx++) {
        float s = 0.f;
        #pragma unroll
        for (int c = 0; c < 4; c++) s += cen[c] * r[c + dx + 4];
        acc[5 + (dy - 1) * 9 + dx + 4] += s;
      }
    }
  }
  int wave = tid >> 6, lane = tid & 63;
  #pragma unroll
  for (int k = 0; k < 41; k++) {
    float x = acc[k];
    #pragma unroll
    for (int o = 32; o; o >>= 1) x += __shfl_down(x, o, 64);
    if (lane == 0) fred[wave * 41 + k] = x;
  }
  __syncthreads();
  for (int k = tid; k < 41; k += 256)
    atomicAdd(&g[k], (double)(fred[k] + fred[41 + k] + fred[82 + k] + fred[123 + k]));
}

// raw Grams of 4 band planes (partitioned sinks)
__global__ __launch_bounds__(256, 4) void k_gram4(const float2* __restrict__ b0, const float2* __restrict__ b1,
                                                  const float2* __restrict__ b2, const float2* __restrict__ b3,
                                                  int n, double* c0out, double* crout) {
  __shared__ float red[128];
  int part = blockIdx.x & (NP - 1);
  float acc[32];
  #pragma unroll
  for (int k = 0; k < 32; k++) acc[k] = 0.f;
  for (int i = blockIdx.x * 256 + threadIdx.x; i < n; i += gridDim.x * 256) {
    float2 v0 = b0[i], v1 = b1[i], v2 = b2[i], v3 = b3[i];
    float a[4] = { sqrtf(v0.x * v0.x + v0.y * v0.y), sqrtf(v1.x * v1.x + v1.y * v1.y),
                   sqrtf(v2.x * v2.x + v2.y * v2.y), sqrtf(v3.x * v3.x + v3.y * v3.y) };
    float r[4] = { v0.x, v1.x, v2.x, v3.x };
    #pragma unroll
    for (int ii = 0; ii < 4; ii++)
      #pragma unroll
      for (int jj = 0; jj < 4; jj++) { acc[ii * 4 + jj] += a[ii] * a[jj]; acc[16 + ii * 4 + jj] += r[ii] * r[jj]; }
  }
  blk_reduce<32>(acc, red);
  int tid = threadIdx.x;
  if (tid < 16) atomicAdd(&c0out[tid * NP + part], (double)red[tid]);
  else if (tid < 32) atomicAdd(&crout[(tid - 16) * NP + part], (double)red[tid]);
}

__global__ __launch_bounds__(256, 4) void k_dots_rpar5(const float2* __restrict__ P,
                                                       const float2* __restrict__ b0, const float2* __restrict__ b1,
                                                       const float2* __restrict__ b2, const float2* __restrict__ b3,
                                                       double* crxB) {
  __shared__ float red[80];
  int part = blockIdx.x & (NP - 1);
  float acc[20];
  #pragma unroll
  for (int k = 0; k < 20; k++) acc[k] = 0.f;
  for (int i = blockIdx.x * 256 + threadIdx.x; i < 16384; i += gridDim.x * 256) {
    int y = i >> 7, x = i & 127;
    float tt[5];
    tt[0] = P[i].x;
    tt[1] = P[(y << 7) | ((x - 1) & 127)].x;
    tt[2] = P[(y << 7) | ((x + 1) & 127)].x;
    tt[3] = P[(((y - 1) & 127) << 7) | x].x;
    tt[4] = P[(((y + 1) & 127) << 7) | x].x;
    float r[4] = { b0[i].x, b1[i].x, b2[i].x, b3[i].x };
    #pragma unroll
    for (int a = 0; a < 4; a++)
      #pragma unroll
      for (int c = 0; c < 5; c++) acc[a * 5 + c] += r[a] * tt[c];
  }
  blk_reduce<20>(acc, red);
  int tid = threadIdx.x;
  if (tid < 20) atomicAdd(&crxB[((tid / 5) * 8 + (tid % 5)) * NP + part], (double)red[tid]);
}
__global__ __launch_bounds__(256, 4) void k_gram5(const float2* __restrict__ P, double* cr5) {
  __shared__ float red[100];
  int part = blockIdx.x & (NP - 1);
  float acc[25];
  #pragma unroll
  for (int k = 0; k < 25; k++) acc[k] = 0.f;
  for (int i = blockIdx.x * 256 + threadIdx.x; i < 16384; i += gridDim.x * 256) {
    int y = i >> 7, x = i & 127;
    float tt[5];
    tt[0] = P[i].x;
    tt[1] = P[(y << 7) | ((x - 1) & 127)].x;
    tt[2] = P[(y << 7) | ((x + 1) & 127)].x;
    tt[3] = P[(((y - 1) & 127) << 7) | x].x;
    tt[4] = P[(((y + 1) & 127) << 7) | x].x;
    #pragma unroll
    for (int a = 0; a < 5; a++)
      #pragma unroll
      for (int c = 0; c < 5; c++) acc[a * 5 + c] += tt[a] * tt[c];
  }
  blk_reduce<25>(acc, red);
  int tid = threadIdx.x;
  if (tid < 25) atomicAdd(&cr5[tid * NP + part], (double)red[tid]);
}

// ================= finalize (sums partitions) =================
__global__ __launch_bounds__(256) void k_finalize(const double* __restrict__ stg, const unsigned* __restrict__ stgu,
                                                  float* __restrict__ out) {
  int t = blockIdx.x * 256 + threadIdx.x;
  if (t >= 2456) return;
  const double N = 1048576.0;
  auto sumP = [&](int base) -> double {
    double s = 0.0;
    #pragma unroll
    for (int k = 0; k < NP; k++) s += stg[base + k];
    return s;
  };
  double m1 = sumP(SG_PIX) / N, m2 = sumP(SG_PIX + NP) / N;
  double vp = m2 - m1 * m1;
  if (t < 6) {
    double m3 = sumP(SG_PIX + 2 * NP) / N, m4 = sumP(SG_PIX + 3 * NP) / N;
    double cm3 = m3 - 3.0 * m1 * m2 + 2.0 * m1 * m1 * m1;
    double cm4 = m4 - 4.0 * m1 * m3 + 6.0 * m1 * m1 * m2 - 3.0 * m1 * m1 * m1 * m1;
    double r;
    if (t == 0) r = m1;
    else if (t == 1) r = vp * (N / (N - 1.0));
    else if (t == 2) r = cm3 / (vp * sqrt(vp));
    else if (t == 3) r = cm4 / (vp * vp);
    else if (t == 4) {
      unsigned k = 0xFFFFFFFFu;
      for (int i = 0; i < NP; i++) k = min(k, stgu[NP + i]);
      r = (double)funkey(k);
    } else {
      unsigned k = 0u;
      for (int i = 0; i < NP; i++) k = max(k, stgu[i]);
      r = (double)funkey(k);
    }
    out[t] = (float)r;
  } else if (t < 24) {
    int i = t - 6;
    double csz;
    if (i == 0) csz = 1048576.0;
    else if (i < 17) { int s = (i - 1) >> 2; double h = (double)(1024 >> s); csz = h * h; }
    else csz = 4096.0;
    out[t] = (float)(sumP(SG_MAG + i * NP) / csz);
  } else if (t < 1320) {
    int e = t - 24;
    int b = e & 3, s = (e >> 2) & 3, o = e >> 4;
    double h = (double)(1024 >> s); double csz = h * h;
    double m = sumP(SG_MAG + (1 + 4 * s + b) * NP) / csz;
    int pi = s * 4 + b;
    int so = sidx(o);
    double sum = stg[SG_ACP + (0 * 21 + pi) * 41 + so] + stg[SG_ACP + (1 * 21 + pi) * 41 + so]
               + stg[SG_ACP + (2 * 21 + pi) * 41 + so] + stg[SG_ACP + (3 * 21 + pi) * 41 + so];
    out[t] = (float)(sum / csz - m * m);
  } else if (t < 1330) {
    int kurt = (t >= 1325);
    int s = t - (kurt ? 1325 : 1320);
    double h = (double)(1024 >> s); double csz = h * h;
    double vari = sumP(SG_IMM + (s * 3) * NP) / csz;
    double var0 = vp * (N / (N - 1.0));
    double v = vari > 1e-12 ? vari : 1e-12;
    double r;
    if (vari / var0 > 1e-6)
      r = kurt ? (sumP(SG_IMM + (s * 3 + 2) * NP) / csz) / (v * v)
               : (sumP(SG_IMM + (s * 3 + 1) * NP) / csz) / (v * sqrt(v));
    else
      r = kurt ? 3.0 : 0.0;
    out[t] = (float)r;
  } else if (t < 1735) {
    int e = t - 1330;
    int s = e % 5, o = e / 5;
    double h = (double)(1024 >> s);
    int pi = 16 + s;
    int so = sidx(o);
    double sum = stg[SG_ACP + (0 * 21 + pi) * 41 + so] + stg[SG_ACP + (1 * 21 + pi) * 41 + so]
               + stg[SG_ACP + (2 * 21 + pi) * 41 + so] + stg[SG_ACP + (3 * 21 + pi) * 41 + so];
    out[t] = (float)(sum / (h * h));
  } else if (t < 1815) {
    int e = t - 1735;
    int s = e % 5, o = e / 5;
    if (s < 4) {
      double h = (double)(1024 >> s); double csz = h * h;
      int i = o >> 2, j = o & 3;
      double mi = sumP(SG_MAG + (1 + 4 * s + i) * NP) / csz;
      double mj = sumP(SG_MAG + (1 + 4 * s + j) * NP) / csz;
      out[t] = (float)(sumP(SG_C0 + (s * 16 + o) * NP) / csz - mi * mj);
    } else out[t] = 0.0f;
  } else if (t < 1879) {
    int e = t - 1815;
    int s = e & 3, o = e >> 2;
    if (s < 3) {
      double h = (double)(1024 >> s); double csz = h * h;
      int c = o >> 2, b = o & 3;
      double mc = sumP(SG_MAG + (1 + 4 * s + c) * NP) / csz;
      double pm = sumP(SG_PMAG + (4 * s + b) * NP) / csz;
      out[t] = (float)(sumP(SG_CX + (s * 16 + o) * NP) / csz - mc * pm);
    } else out[t] = 0.0f;
  } else if (t < 2199) {
    int e = t - 1879;
    int s = e % 5, o = e / 5;
    int i = o >> 3, j = o & 7;
    float r = 0.0f;
    if (s < 4) { if (i < 4 && j < 4) { double h = (double)(1024 >> s); r = (float)(sumP(SG_CR + (s * 16 + i * 4 + j) * NP) / (h * h)); } }
    else { if (i < 5 && j < 5) r = (float)(sumP(SG_CR5 + (i * 5 + j) * NP) / 4096.0); }
    out[t] = r;
  } else if (t < 2455) {
    int e = t - 2199;
    int s = e & 3, o = e >> 2;
    int i = o >> 3, j = o & 7;
    float r = 0.0f;
    if (i < 4) {
      if (s < 3) { double h = (double)(1024 >> s); r = (float)(sumP(SG_CRX + (s * 32 + i * 8 + j) * NP) / (h * h)); }
      else if (j < 5) r = (float)(sumP(SG_CRX + (96 + i * 8 + j) * NP) / 16384.0);
    }
    out[t] = r;
  } else {
    out[t] = (float)(sumP(SG_HISQ) / N);
  }
}

// ================= host orchestration =================
static inline int rb(int n) { int b = (n + 255) / 256; return b > 256 ? 256 : b; }

struct Bufs {
  const float* img;
  float2* L[5];
  float2* Wg;
  double* stg; unsigned* stgu;
  float* out;
  char* w1;   // 40 MiB, 5 x 8MiB slots
  char* w2;   // 32 MiB, 4 x 8MiB slots
  char* l0raw;
};

template<int N>
static void scale_phase(const Bufs& B, int s, hipStream_t st) {
  constexpr int RPB = FftConst<N>::RPB;
  constexpr size_t PB = (size_t)N * N * 8;
  const int np = (N == 128) ? 6 : 5;
  // --- passA: {im, B0..3 [, Plo]} ---
  { PAp a{}; a.twg = B.Wg;
    a.in[0] = B.L[s]; a.mode[0] = MA_IM; a.aux[0] = 0;
    for (int b = 0; b < 4; b++) { a.in[1 + b] = B.L[s]; a.mode[1 + b] = MA_BAND; a.aux[1 + b] = b; }
    if (np == 6) { a.in[5] = B.L[4]; a.mode[5] = MA_EMBED_LO; a.aux[5] = 0; }
    for (int p = 0; p < np; p++) a.out[p] = (float2*)(B.w1 + p * PB);
    k_passA<N, true><<<dim3(N / RPB, np), 256, 0, st>>>(a); }
  // --- transpose ---
  float2* D[6];
  { TPp t{};
    for (int p = 0; p < np; p++) {
      D[p] = (N <= 512 || p < 4) ? (float2*)(B.w2 + p * PB) : (float2*)B.l0raw;
      t.src[p] = (const float2*)(B.w1 + p * PB); t.dst[p] = D[p];
    }
    k_transpose<<<dim3(N / 32, N / 32, np), 256, 0, st>>>(t, N); }
  // --- passB: spatial + fused stats ---
  { PBp bb{}; bb.twg = B.Wg;
    for (int p = 0; p < np; p++) { bb.in[p] = D[p]; bb.out[p] = (float2*)(B.w1 + p * PB); }
    bb.wmode[0] = WB_WRITE_IM; bb.red[0] = B.stg + SG_IMM + (s * 3) * NP;
    for (int b = 0; b < 4; b++) { bb.wmode[1 + b] = WB_WRITE_MAG; bb.red[1 + b] = B.stg + SG_MAG + (1 + 4 * s + b) * NP; }
    if (np == 6) bb.wmode[5] = WB_WRITE;
    k_passB<N, true><<<dim3(N / RPB, np), 256, 0, st>>>(bb); }
  // --- autocorr (im + 4 bands), 4-way partitioned symmetric raw sums ---
  { ACp c{};
    c.in[0] = (const float2*)(B.w1); c.pi[0] = 16 + s; c.mode[0] = 0;
    for (int b = 0; b < 4; b++) { c.in[1 + b] = (const float2*)(B.w1 + (1 + b) * PB); c.pi[1 + b] = s * 4 + b; c.mode[1 + b] = 1; }
    int nT = (N / 32) * (N / 32);
    k_autocorr<<<dim3(nT > 256 ? 256 : nT, 5), 256, 0, st>>>(c, N, B.stg + SG_ACP); }
  // --- raw gram ---
  k_gram4<<<rb(N * N), 256, 0, st>>>((const float2*)(B.w1 + PB), (const float2*)(B.w1 + 2 * PB),
                                     (const float2*)(B.w1 + 3 * PB), (const float2*)(B.w1 + 4 * PB),
                                     N * N, B.stg + SG_C0 + s * 16 * NP, B.stg + SG_CR + s * 16 * NP);
  if (s < 3) {
    // --- parents: one 4-plane passA, then 2x (transpose + pdots passB) ---
    { PAp a{}; a.twg = B.Wg;
      for (int b = 0; b < 4; b++) { a.in[b] = B.L[s + 1]; a.mode[b] = MA_EMBED_BAND; a.aux[b] = b; a.out[b] = (float2*)(B.w2 + b * PB); }
      k_passA<N, true><<<dim3(N / RPB, 4), 256, 0, st>>>(a); }
    char* td0; char* td1;
    if (N == 1024) { td0 = B.l0raw; td1 = B.w1; }
    else { td0 = B.w2 + 4 * PB; td1 = B.w2 + 5 * PB; }
    for (int pr = 0; pr < 2; pr++) {
      { TPp t{};
        t.src[0] = (const float2*)(B.w2 + (2 * pr) * PB); t.dst[0] = (float2*)td0;
        t.src[1] = (const float2*)(B.w2 + (2 * pr + 1) * PB); t.dst[1] = (float2*)td1;
        k_transpose<<<dim3(N / 32, N / 32, 2), 256, 0, st>>>(t, N); }
      { PBp bb{}; bb.twg = B.Wg;
        bb.in[0] = (const float2*)td0; bb.in[1] = (const float2*)td1;
        for (int k = 0; k < 2; k++) { int b = pr * 2 + k; bb.wmode[k] = WB_PDOTS; bb.aux[k] = b; bb.red[k] = B.stg + SG_PMAG + (4 * s + b) * NP; }
        for (int cc = 0; cc < 4; cc++) bb.Bp[cc] = (const float2*)(B.w1 + (1 + cc) * PB);
        bb.cx = B.stg + SG_CX + s * 16 * NP; bb.crx = B.stg + SG_CRX + s * 32 * NP;
        k_passB<N, true><<<dim3(N / RPB, 2), 256, 0, st>>>(bb); }
    }
  } else {
    k_dots_rpar5<<<64, 256, 0, st>>>((const float2*)(B.w1 + 5 * PB),
                                     (const float2*)(B.w1 + PB), (const float2*)(B.w1 + 2 * PB),
                                     (const float2*)(B.w1 + 3 * PB), (const float2*)(B.w1 + 4 * PB),
                                     B.stg + SG_CRX + 96 * NP);
    k_gram5<<<64, 256, 0, st>>>((const float2*)(B.w1 + 5 * PB), B.stg + SG_CR5);
  }
}

extern "C" void kernel_launch(void* const* d_in, const int* in_sizes, int n_in,
                              void* d_out, int out_size, void* d_ws, size_t ws_size,
                              hipStream_t stream) {
  (void)in_sizes; (void)n_in; (void)out_size;
  if (ws_size < 87031808ull) return;   // 83 MiB
  char* w = (char*)d_ws;
  Bufs B;
  B.img = (const float*)d_in[0];
  B.out = (float*)d_out;
  B.L[0] = (float2*)(w + 0ull);
  B.L[1] = (float2*)(w + 8388608ull);
  B.L[2] = (float2*)(w + 10485760ull);
  B.L[3] = (float2*)(w + 11010048ull);
  B.L[4] = (float2*)(w + 11141120ull);
  B.Wg   = (float2*)(w + 11173888ull);
  B.stg  = (double*)(w + 11177984ull);
  B.stgu = (unsigned*)(B.stg + NSTG);
  B.w1   = w + 11534336ull;            // 40 MiB
  B.w2   = w + 53477376ull;            // 32 MiB
  B.l0raw = w;
  hipStream_t st = stream;
  double* stg = B.stg;
  constexpr size_t PB8 = 8388608ull;

  k_init<<<(NSTG + 255) / 256, 256, 0, st>>>(stg, B.stgu, B.Wg);

  // forward fft2 with fused pixel raw moments
  k_fwdA<<<1024, 256, 0, st>>>(B.img, (float2*)(B.w1), B.Wg, stg, B.stgu);
  { TPp t{}; t.src[0] = (const float2*)(B.w1); t.dst[0] = (float2*)(B.w2);
    k_transpose<<<dim3(32, 32, 1), 256, 0, st>>>(t, 1024); }
  { PBp bb{}; bb.twg = B.Wg; bb.in[0] = (const float2*)(B.w2); bb.wmode[0] = WB_FWD_MASK;
    bb.out[0] = (float2*)(B.w1 + PB8); bb.out2 = B.L[0];
    k_passB<1024, false><<<dim3(1024, 1), 256, 0, st>>>(bb); }

  // hi residual: ifft2 of hi-spec, reduce-only (sum|re|, re^2)
  { PAp a{}; a.twg = B.Wg; a.in[0] = (const float2*)(B.w1 + PB8); a.mode[0] = MA_C2; a.aux[0] = 0;
    a.out[0] = (float2*)(B.w1);
    k_passA<1024, true><<<dim3(1024, 1), 256, 0, st>>>(a); }
  { TPp t{}; t.src[0] = (const float2*)(B.w1); t.dst[0] = (float2*)(B.w2);
    k_transpose<<<dim3(32, 32, 1), 256, 0, st>>>(t, 1024); }
  { PBp bb{}; bb.twg = B.Wg; bb.in[0] = (const float2*)(B.w2); bb.wmode[0] = WB_RED_HI;
    bb.red[0] = stg + SG_MAG; bb.red2 = stg + SG_HISQ;
    k_passB<1024, true><<<dim3(1024, 1), 256, 0, st>>>(bb); }

  // lowpass chain, single dispatch
  k_ldown<<<1360, 256, 0, st>>>(B.L[0], B.L[1], B.L[2], B.L[3], B.L[4]);

  // size-64 batch: {lo-resid (plain ifft of L4), imF4 = L4*lo0}
  {
    constexpr size_t PB = 64ull * 64ull * 8ull;
    constexpr int RPB = FftConst<64>::RPB;
    { PAp a{}; a.twg = B.Wg;
      a.in[0] = B.L[4]; a.mode[0] = MA_C2; a.aux[0] = 0; a.out[0] = (float2*)(B.w1);
      a.in[1] = B.L[4]; a.mode[1] = MA_IMF4; a.aux[1] = 0; a.out[1] = (float2*)(B.w1 + PB);
      k_passA<64, true><<<dim3(64 / RPB, 2), 256, 0, st>>>(a); }
    { TPp t{};
      t.src[0] = (const float2*)(B.w1); t.dst[0] = (float2*)(B.w2);
      t.src[1] = (const float2*)(B.w1 + PB); t.dst[1] = (float2*)(B.w2 + PB);
      k_transpose<<<dim3(2, 2, 2), 256, 0, st>>>(t, 64); }
    { PBp bb{}; bb.twg = B.Wg;
      bb.in[0] = (const float2*)(B.w2); bb.wmode[0] = WB_RED_ABSRE; bb.red[0] = stg + SG_MAG + 17 * NP;
      bb.in[1] = (const float2*)(B.w2 + PB); bb.wmode[1] = WB_WRITE_IM; bb.red[1] = stg + SG_IMM + 12 * NP;
      bb.out[1] = (float2*)(B.w1 + PB);
      k_passB<64, true><<<dim3(64 / RPB, 2), 256, 0, st>>>(bb); }
    { ACp c{}; c.in[0] = (const float2*)(B.w1 + PB); c.pi[0] = 20; c.mode[0] = 0;
      k_autocorr<<<dim3(4, 1), 256, 0, st>>>(c, 64, stg + SG_ACP); }
  }

  // per-scale batches
  scale_phase<128>(B, 3, st);
  scale_phase<256>(B, 2, st);
  scale_phase<512>(B, 1, st);
  scale_phase<1024>(B, 0, st);

  k_finalize<<<10, 256, 0, st>>>(stg, B.stgu, B.out);
}

// Round 9
// 607.129 us; speedup vs baseline: 1.5692x; 1.1335x over previous
//
#include <hip/hip_runtime.h>
#include <math.h>

#define PI_F      3.14159265358979323846f
#define TWOPI_F   6.28318530717958647692f
#define HALFPI_F  1.57079632679489661923f
#define ANG_F     0.8944271909999159f

// ---- staging: [NP partitions][PSZ doubles] so concurrent atomics from different
// partitions hit different L2 cache lines/channels. Item offsets within a partition:
#define NP       32
#define PSZ      512            // 4 KiB stride per partition
#define PP_PIX   0              // [4]
#define PP_MAG   4              // [18]
#define PP_HISQ  22             // [1]
#define PP_PMAG  23             // [12]
#define PP_IMM   35             // [15]
#define PP_C0    50             // [4][16]
#define PP_CR    114            // [4][16]
#define PP_CX    178            // [3][16]
#define PP_CRX   226            // [4][32]
#define PP_CR5   354            // [25]
#define SG_ACP   (NP * PSZ)     // autocorr: [ACPART][21 planes][ACSTRIDE]
#define ACPART   8
#define ACSTRIDE 64
#define NSTG     (SG_ACP + ACPART * 21 * ACSTRIDE)

enum { MA_C2 = 0, MA_REAL, MA_BAND, MA_EMBED_BAND, MA_EMBED_LO, MA_IMF4, MA_IM };
enum { WB_WRITE = 0, WB_WRITE_MAG, WB_WRITE_IM, WB_RED_HI, WB_RED_ABSRE, WB_FWD_MASK, WB_PDOTS };

__device__ __forceinline__ int sfreq(int k, int H) { return (k < (H >> 1)) ? k : k - H; }
__device__ __forceinline__ int skx(int i) { return i + (i >> 4); }   // LDS bank skew

__device__ __forceinline__ float d_lograd(int fy, int fx, int H) {
  float cy = (float)fy * (2.0f / (float)H);
  float cx = (float)fx * (2.0f / (float)H);
  float rad = sqrtf(cx * cx + cy * cy);
  if (fy == 0 && fx == 0) rad = 2.0f / (float)H;   // reference DC hack
  return log2f(rad);
}
__device__ __forceinline__ float d_angle(int fy, int fx, int H) {
  return atan2f((float)fy * (2.0f / (float)H), (float)fx * (2.0f / (float)H));
}
__device__ __forceinline__ float d_rc(float x) {
  float c = fminf(fmaxf(-x, 0.0f), 1.0f);
  float t = cosf(0.5f * PI_F * c);
  return t * t;
}
__device__ __forceinline__ float d_alfa(float ang, int b) {
  float bc = (b == 0) ? 0.0f : (b == 1) ? 0.78539816339744830962f
           : (b == 2) ? 1.57079632679489661923f : 2.35619449019234492885f;
  float t = (PI_F + ang) - bc;
  float m = fmodf(t, TWOPI_F);
  if (m < 0.0f) m += TWOPI_F;
  return m - PI_F;
}
__device__ __forceinline__ float d_cos3(float a) { float c = cosf(a); return ANG_F * c * c * c; }
__device__ __forceinline__ float d_amaskC(float ang, int b) {
  float alfa = d_alfa(ang, b);
  float A = d_cos3(alfa);
  return (fabsf(alfa) < HALFPI_F) ? 2.0f * A : 0.0f;
}
__device__ __forceinline__ float d_lo(int fy, int fx, int H) {
  return sqrtf(fmaxf(1.0f - d_rc(d_lograd(fy, fx, H)), 0.0f));
}
// recon mask at native size H
__device__ __forceinline__ float d_mm(int fy, int fx, int H) {
  float lr = d_lograd(fy, fx, H);
  float hm2 = d_rc(lr + 1.0f);
  float lo0 = sqrtf(fmaxf(1.0f - d_rc(lr), 0.0f));
  float ang1 = d_angle(fy, fx, H);
  int gfy = (fy == -(H >> 1)) ? fy : -fy;
  int gfx = (fx == -(H >> 1)) ? fx : -fx;
  float ang2 = d_angle(gfy, gfx, H);
  float msum = 0.0f;
  #pragma unroll
  for (int b4 = 0; b4 < 4; b4++) {
    float a1 = d_alfa(ang1, b4), a2 = d_alfa(ang2, b4);
    float A1 = d_cos3(a1), A2 = d_cos3(a2);
    float T1 = (fabsf(a1) < HALFPI_F) ? A1 : 0.0f;
    float T2 = (fabsf(a2) < HALFPI_F) ? A2 : 0.0f;
    msum += A1 * (T1 - T2);
  }
  return lo0 * hm2 * msum;
}
// accumulated im-chain mask at scale with native size N (N>=128)
template<int N>
__device__ __forceinline__ float d_G(int fy, int fx) {
  float g = d_mm(fy, fx, N);
  float chain = 1.0f;
  #pragma unroll
  for (int Nj = (N >> 1); Nj >= 64; Nj >>= 1) {
    int h = Nj >> 1;
    if (fy < -h || fy >= h || fx < -h || fx >= h) break;
    chain *= d_lo(fy, fx, Nj);
    if (Nj > 64) g += chain * d_mm(fy, fx, Nj);
    else g += chain * d_lo(fy, fx, 64);
  }
  if (fy == 0 && fx == 0) g = 0.0f;
  return g;
}
__device__ __forceinline__ unsigned fkey(float f) {
  unsigned u = __float_as_uint(f);
  return (u & 0x80000000u) ? ~u : (u | 0x80000000u);
}
__device__ __forceinline__ float funkey(unsigned k) {
  return (k & 0x80000000u) ? __uint_as_float(k & 0x7FFFFFFFu) : __uint_as_float(~k);
}
// map full 9x9 offset index (0..80) to symmetric 41-index
__device__ __forceinline__ int sidx(int o) {
  int dy = o / 9 - 4, dx = o - (o / 9) * 9 - 4;
  if (dy < 0 || (dy == 0 && dx < 0)) { dy = -dy; dx = -dx; }
  return (dy == 0) ? dx : 5 + (dy - 1) * 9 + dx + 4;
}

template<int K>
__device__ __forceinline__ void blk_reduce(float* v, float* red) {
  int tid = threadIdx.x, wave = tid >> 6, lane = tid & 63;
  #pragma unroll
  for (int k = 0; k < K; k++) {
    float x = v[k];
    #pragma unroll
    for (int o = 32; o; o >>= 1) x += __shfl_down(x, o, 64);
    if (lane == 0) red[wave * K + k] = x;
  }
  __syncthreads();
  if (tid < K) red[tid] = red[tid] + red[K + tid] + red[2 * K + tid] + red[3 * K + tid];
}

// ================= FFT core (Stockham, radix-4 with leading radix-2) =================
template<int N> struct FftConst {
  static constexpr int L2N = (N == 64) ? 6 : (N == 128) ? 7 : (N == 256) ? 8 : (N == 512) ? 9 : 10;
  static constexpr int TPR = (N / 4 >= 256) ? 256 : ((N / 4 < 16) ? 16 : N / 4);
  static constexpr int RPB = 256 / TPR;
  static constexpr int BUF = N + (N >> 4);
};

template<int N, bool INV>
__device__ __forceinline__ float2* fft_core(float2* A, float2* B, const float2* tw, int tr) {
  constexpr int TPR = FftConst<N>::TPR;
  constexpr int L2N = FftConst<N>::L2N;
  float2* src = A; float2* dst = B;
  if constexpr (L2N & 1) {
    for (int t = tr; t < (N >> 1); t += TPR) {
      float2 w = tw[t];
      float cv = w.x, sv = INV ? w.y : -w.y;
      float2 a = src[skx(t)];
      float2 b = src[skx(t + (N >> 1))];
      float dx = a.x - b.x, dy = a.y - b.y;
      dst[skx(2 * t)] = make_float2(a.x + b.x, a.y + b.y);
      dst[skx(2 * t + 1)] = make_float2(dx * cv - dy * sv, dx * sv + dy * cv);
    }
    __syncthreads();
    float2* tmp = src; src = dst; dst = tmp;
  }
  #pragma unroll
  for (int st = (L2N & 1); st < L2N; st += 2) {
    for (int t = tr; t < (N >> 2); t += TPR) {
      int p = t >> st;
      int q = t & ((1 << st) - 1);
      int i0 = q + (p << st);
      float2 x0 = src[skx(i0)];
      float2 x1 = src[skx(i0 + (N >> 2))];
      float2 x2 = src[skx(i0 + (N >> 1))];
      float2 x3 = src[skx(i0 + 3 * (N >> 2))];
      float2 w = tw[p << st];
      float c1 = w.x, s1 = INV ? w.y : -w.y;
      float c2 = c1 * c1 - s1 * s1, s2 = 2.f * c1 * s1;
      float c3 = c2 * c1 - s2 * s1, s3 = c2 * s1 + s2 * c1;
      float e0x = x0.x + x2.x, e0y = x0.y + x2.y;
      float e1x = x0.x - x2.x, e1y = x0.y - x2.y;
      float o0x = x1.x + x3.x, o0y = x1.y + x3.y;
      float d1x = x1.x - x3.x, d1y = x1.y - x3.y;
      float o1x, o1y;
      if constexpr (INV) { o1x = -d1y; o1y = d1x; }
      else               { o1x = d1y;  o1y = -d1x; }
      float t1x = e1x + o1x, t1y = e1y + o1y;
      float t2x = e0x - o0x, t2y = e0y - o0y;
      float t3x = e1x - o1x, t3y = e1y - o1y;
      int o = q + (p << (st + 2));
      int s = 1 << st;
      dst[skx(o)]         = make_float2(e0x + o0x, e0y + o0y);
      dst[skx(o + s)]     = make_float2(t1x * c1 - t1y * s1, t1x * s1 + t1y * c1);
      dst[skx(o + 2 * s)] = make_float2(t2x * c2 - t2y * s2, t2x * s2 + t2y * c2);
      dst[skx(o + 3 * s)] = make_float2(t3x * c3 - t3y * s3, t3x * s3 + t3y * c3);
    }
    __syncthreads();
    float2* tmp = src; src = dst; dst = tmp;
  }
  return src;
}

struct PAp {
  const float2* in[6];
  float2* out[6];
  const float2* twg;
  int mode[6];
  int aux[6];
};
struct PBp {
  const float2* in[6];
  float2* out[6];
  float2* out2;
  const float2* Bp[4];
  double* stg;
  const float2* twg;
  int redo[6];
  int red2o;
  int cxo;
  int crxo;
  int wmode[6];
  int aux[6];
};
struct TPp { const float2* src[6]; float2* dst[6]; };
struct ACp { const float2* in[5]; int pi[5]; int mode[5]; };

template<int N, int MODE>
__device__ __forceinline__ float2 loadA(const float2* in, int row, int i, int b) {
  if constexpr (MODE == MA_C2) {
    return in[(size_t)row * N + i];
  } else if constexpr (MODE == MA_REAL) {
    const float* f = (const float*)in;
    return make_float2(f[(size_t)row * N + i], 0.0f);
  } else if constexpr (MODE == MA_BAND) {
    int fy = sfreq(i, N), fx = sfreq(row, N);
    float m = sqrtf(d_rc(d_lograd(fy, fx, N) + 1.0f)) * d_amaskC(d_angle(fy, fx, N), b);
    float2 l = in[(size_t)row * N + i];
    return make_float2(-l.y * m, l.x * m);
  } else if constexpr (MODE == MA_EMBED_BAND) {
    int fy = sfreq(i, N), fx = sfreq(row, N);
    int q = N >> 2, h2 = N >> 1;
    if (fy < -q || fy >= q || fx < -q || fx >= q) return make_float2(0.f, 0.f);
    int U = fx >= 0 ? fx : fx + h2, V = fy >= 0 ? fy : fy + h2;
    float m = sqrtf(d_rc(d_lograd(fy, fx, h2) + 1.0f)) * d_amaskC(d_angle(fy, fx, h2), b);
    float2 l = in[(size_t)U * h2 + V];
    return make_float2(-l.y * m, l.x * m);
  } else if constexpr (MODE == MA_EMBED_LO) {
    int fy = sfreq(i, N), fx = sfreq(row, N);
    int q = N >> 2, h2 = N >> 1;
    if (fy < -q || fy >= q || fx < -q || fx >= q) return make_float2(0.f, 0.f);
    int U = fx >= 0 ? fx : fx + h2, V = fy >= 0 ? fy : fy + h2;
    return in[(size_t)U * h2 + V];
  } else if constexpr (MODE == MA_IMF4) {
    int fy = sfreq(i, N), fx = sfreq(row, N);
    float lo = d_lo(fy, fx, N);
    float2 v = in[(size_t)row * N + i];
    return make_float2(v.x * lo, v.y * lo);
  } else {  // MA_IM
    int fy = sfreq(i, N), fx = sfreq(row, N);
    float g = d_G<N>(fy, fx);
    float2 l = in[(size_t)row * N + i];
    return make_float2(l.x * g, l.y * g);
  }
}

// pass A: fused load op -> row FFT -> write
template<int N, bool INV>
__global__ __launch_bounds__(256) void k_passA(PAp p) {
  using FC = FftConst<N>;
  __shared__ float2 shA[FC::RPB][FC::BUF];
  __shared__ float2 shB[FC::RPB][FC::BUF];
  __shared__ float2 tw[N / 2];
  int tid = threadIdx.x;
  for (int k = tid; k < N / 2; k += 256) tw[k] = p.twg[k << (10 - FC::L2N)];
  int rl = tid / FC::TPR;
  int tr = tid % FC::TPR;
  int row = blockIdx.x * FC::RPB + rl;
  int plane = blockIdx.y;
  const float2* in = p.in[plane];
  int mode = p.mode[plane];
  int b = p.aux[plane];
  float2* A = shA[rl];
  switch (mode) {
    case MA_C2:         for (int i = tr; i < N; i += FC::TPR) A[skx(i)] = loadA<N, MA_C2>(in, row, i, b); break;
    case MA_REAL:       for (int i = tr; i < N; i += FC::TPR) A[skx(i)] = loadA<N, MA_REAL>(in, row, i, b); break;
    case MA_BAND:       for (int i = tr; i < N; i += FC::TPR) A[skx(i)] = loadA<N, MA_BAND>(in, row, i, b); break;
    case MA_EMBED_BAND: for (int i = tr; i < N; i += FC::TPR) A[skx(i)] = loadA<N, MA_EMBED_BAND>(in, row, i, b); break;
    case MA_EMBED_LO:   for (int i = tr; i < N; i += FC::TPR) A[skx(i)] = loadA<N, MA_EMBED_LO>(in, row, i, b); break;
    case MA_IMF4:       for (int i = tr; i < N; i += FC::TPR) A[skx(i)] = loadA<N, MA_IMF4>(in, row, i, b); break;
    default:            for (int i = tr; i < N; i += FC::TPR) A[skx(i)] = loadA<N, MA_IM>(in, row, i, b); break;
  }
  __syncthreads();
  float2* res = fft_core<N, INV>(A, shB[rl], tw, tr);
  constexpr float sc = INV ? 1.0f / (float)N : 1.0f;
  float2* o = p.out[plane] + (size_t)row * N;
  for (int i = tr; i < N; i += FC::TPR) {
    float2 v = res[skx(i)];
    o[i] = make_float2(v.x * sc, v.y * sc);
  }
}

// forward passA over the raw image with fused raw pixel moments + min/max (strided partitions)
__global__ __launch_bounds__(256) void k_fwdA(const float* __restrict__ img, float2* __restrict__ out,
                                              const float2* __restrict__ twg, double* stg, unsigned* stgu) {
  using FC = FftConst<1024>;
  __shared__ float2 shA[FC::BUF];
  __shared__ float2 shB[FC::BUF];
  __shared__ float2 tw[512];
  __shared__ float red[16];
  int tid = threadIdx.x;
  int part = blockIdx.x & (NP - 1);
  for (int k = tid; k < 512; k += 256) tw[k] = twg[k];
  int row = blockIdx.x;
  float s1 = 0.f, s2 = 0.f, s3 = 0.f, s4 = 0.f;
  float mn = 3.402823466e38f, mx = -3.402823466e38f;
  for (int i = tid; i < 1024; i += 256) {
    float x = img[(size_t)row * 1024 + i];
    shA[skx(i)] = make_float2(x, 0.f);
    float x2 = x * x;
    s1 += x; s2 += x2; s3 += x2 * x; s4 += x2 * x2;
    mn = fminf(mn, x); mx = fmaxf(mx, x);
  }
  float accv[4] = {s1, s2, s3, s4};
  blk_reduce<4>(accv, red);
  if (tid < 4) atomicAdd(&stg[(size_t)part * PSZ + PP_PIX + tid], (double)red[tid]);
  #pragma unroll
  for (int o = 32; o; o >>= 1) { mn = fminf(mn, __shfl_down(mn, o, 64)); mx = fmaxf(mx, __shfl_down(mx, o, 64)); }
  if ((tid & 63) == 0) { atomicMin(&stgu[part * 32 + 1], fkey(mn)); atomicMax(&stgu[part * 32], fkey(mx)); }
  float2* res = fft_core<1024, false>(shA, shB, tw, tid);
  float2* o = out + (size_t)row * 1024;
  for (int i = tid; i < 1024; i += 256) o[i] = res[skx(i)];
}

// pass B: plain load -> row FFT -> write / fused reductions (strided partitions)
template<int N, bool INV>
__global__ __launch_bounds__(256) void k_passB(PBp p) {
  using FC = FftConst<N>;
  __shared__ float2 shA[FC::RPB][FC::BUF];
  __shared__ float2 shB[FC::RPB][FC::BUF];
  __shared__ float2 tw[N / 2];
  __shared__ float red[52];
  int tid = threadIdx.x;
  double* base = p.stg + (size_t)(blockIdx.x & (NP - 1)) * PSZ;
  for (int k = tid; k < N / 2; k += 256) tw[k] = p.twg[k << (10 - FC::L2N)];
  int rl = tid / FC::TPR;
  int tr = tid % FC::TPR;
  int row = blockIdx.x * FC::RPB + rl;
  int plane = blockIdx.y;
  const float2* in = p.in[plane] + (size_t)row * N;
  float2* A = shA[rl];
  for (int i = tr; i < N; i += FC::TPR) A[skx(i)] = in[i];
  __syncthreads();
  float2* res = fft_core<N, INV>(A, shB[rl], tw, tr);
  constexpr float sc = INV ? 1.0f / (float)N : 1.0f;
  int wmode = p.wmode[plane];
  if (wmode == WB_WRITE || wmode == WB_WRITE_MAG || wmode == WB_WRITE_IM) {
    float2* o = p.out[plane] + (size_t)row * N;
    float a0 = 0.f, a1 = 0.f, a2 = 0.f;
    for (int i = tr; i < N; i += FC::TPR) {
      float2 v = res[skx(i)];
      v.x *= sc; v.y *= sc;
      o[i] = v;
      if (wmode == WB_WRITE_MAG) a0 += sqrtf(v.x * v.x + v.y * v.y);
      else if (wmode == WB_WRITE_IM) { float v2 = v.x * v.x; a0 += v2; a1 += v2 * v.x; a2 += v2 * v2; }
    }
    if (wmode == WB_WRITE_MAG) {
      float acc[1] = {a0}; blk_reduce<1>(acc, red);
      if (tid == 0) atomicAdd(&base[p.redo[plane]], (double)red[0]);
    } else if (wmode == WB_WRITE_IM) {
      float acc[3] = {a0, a1, a2}; blk_reduce<3>(acc, red);
      if (tid < 3) atomicAdd(&base[p.redo[plane] + tid], (double)red[tid]);
    }
  } else if (wmode == WB_RED_HI) {
    float a0 = 0.f, a1 = 0.f;
    for (int i = tr; i < N; i += FC::TPR) {
      float v = res[skx(i)].x * sc;
      a0 += fabsf(v); a1 += v * v;
    }
    float acc[2] = {a0, a1}; blk_reduce<2>(acc, red);
    if (tid == 0) atomicAdd(&base[p.redo[plane]], (double)red[0]);
    if (tid == 1) atomicAdd(&base[p.red2o], (double)red[1]);
  } else if (wmode == WB_RED_ABSRE) {
    float a0 = 0.f;
    for (int i = tr; i < N; i += FC::TPR) a0 += fabsf(res[skx(i)].x * sc);
    float acc[1] = {a0}; blk_reduce<1>(acc, red);
    if (tid == 0) atomicAdd(&base[p.redo[plane]], (double)red[0]);
  } else if (wmode == WB_FWD_MASK) {
    float2* o1 = p.out[plane] + (size_t)row * N;
    float2* o2 = p.out2 + (size_t)row * N;
    int fx = sfreq(row, N);
    for (int i = tr; i < N; i += FC::TPR) {
      float2 v = res[skx(i)];
      int fy = sfreq(i, N);
      float rcv = d_rc(d_lograd(fy, fx, N));
      float hi = sqrtf(rcv), lo = sqrtf(fmaxf(1.0f - rcv, 0.0f));
      o1[i] = make_float2(v.x * hi, v.y * hi);
      o2[i] = make_float2(v.x * lo, v.y * lo);
    }
  } else {  // WB_PDOTS
    int b = p.aux[plane];
    float acc[13];
    #pragma unroll
    for (int k = 0; k < 13; k++) acc[k] = 0.f;
    for (int i = tr; i < N; i += FC::TPR) {
      float2 v = res[skx(i)];
      v.x *= sc; v.y *= sc;
      float mag = sqrtf(v.x * v.x + v.y * v.y);
      float rr = 0.f, ri = 0.f;
      if (mag > 0.f) { rr = (v.y * v.y - v.x * v.x) / mag; ri = 2.f * v.x * v.y / mag; }
      size_t idx = (size_t)row * N + i;
      #pragma unroll
      for (int c = 0; c < 4; c++) {
        float2 bv = p.Bp[c][idx];
        float am = sqrtf(bv.x * bv.x + bv.y * bv.y);
        acc[c] += am * mag;
        acc[4 + c] += bv.x * rr;
        acc[8 + c] += bv.x * ri;
      }
      acc[12] += mag;
    }
    blk_reduce<13>(acc, red);
    if (tid < 4) atomicAdd(&base[p.cxo + tid * 4 + b], (double)red[tid]);
    else if (tid < 8) atomicAdd(&base[p.crxo + (tid - 4) * 8 + b], (double)red[tid]);
    else if (tid < 12) atomicAdd(&base[p.crxo + (tid - 8) * 8 + 4 + b], (double)red[tid]);
    else if (tid == 12) atomicAdd(&base[p.redo[plane]], (double)red[12]);
  }
}

__global__ __launch_bounds__(256) void k_transpose(TPp p, int N) {
  __shared__ float2 tile[32][33];
  int z = blockIdx.z;
  const float2* in = p.src[z];
  float2* out = p.dst[z];
  int bx = blockIdx.x << 5, by = blockIdx.y << 5;
  int tx = threadIdx.x & 31, ty = threadIdx.x >> 5;
  for (int r = ty; r < 32; r += 8) tile[r][tx] = in[(size_t)(by + r) * N + bx + tx];
  __syncthreads();
  for (int r = ty; r < 32; r += 8) out[(size_t)(bx + r) * N + by + tx] = tile[tx][r];
}

// all 4 lowpass levels from L0 in one dispatch (cumulative masks)
__global__ __launch_bounds__(256) void k_ldown(const float2* __restrict__ L0,
                                               float2* __restrict__ L1, float2* __restrict__ L2,
                                               float2* __restrict__ L3, float2* __restrict__ L4) {
  int idx = blockIdx.x * 256 + threadIdx.x;
  int s, N, i;
  float2* dst;
  if (idx < 262144)      { s = 1; N = 512; i = idx;          dst = L1; }
  else if (idx < 327680) { s = 2; N = 256; i = idx - 262144; dst = L2; }
  else if (idx < 344064) { s = 3; N = 128; i = idx - 327680; dst = L3; }
  else if (idx < 348160) { s = 4; N = 64;  i = idx - 344064; dst = L4; }
  else return;
  int fy = sfreq(i / N, N), fx = sfreq(i % N, N);
  float m = 1.0f;
  for (int j = 1; j <= s; j++) m *= d_lo(fy, fx, 1024 >> j);
  int by = fy >= 0 ? fy : fy + 1024;
  int bx = fx >= 0 ? fx : fx + 1024;
  float2 v = L0[(size_t)by * 1024 + bx];
  if (s == 4 && i == 0) { dst[0] = make_float2(0.f, 0.f); return; }
  dst[i] = make_float2(v.x * m, v.y * m);
}

// ================= reductions / stats =================
__global__ __launch_bounds__(256) void k_init(double* stg, unsigned* stgu, float2* Wg) {
  int i = blockIdx.x * 256 + threadIdx.x;
  if (i < NSTG) stg[i] = 0.0;
  if (i < NP) { stgu[i * 32] = 0u; stgu[i * 32 + 1] = 0xFFFFFFFFu; }
  if (i < 512) {
    float a = TWOPI_F * (float)i * (1.0f / 1024.0f);
    float sv, cv; sincosf(a, &sv, &cv);
    Wg[i] = make_float2(cv, sv);
  }
}

// central 9x9 circular autocorrelation, RAW sums, symmetry-halved (41 offsets).
__global__ __launch_bounds__(256, 3) void k_autocorr(ACp p, int H, double* acp) {
  __shared__ float tile[40][41];
  __shared__ float fred[4 * 41];
  const int plane = blockIdx.y;
  const float2* __restrict__ in = p.in[plane];
  const int mode = p.mode[plane];
  double* g = acp + ((size_t)((blockIdx.x & (ACPART - 1)) * 21 + p.pi[plane])) * ACSTRIDE;
  float acc[41];
  #pragma unroll
  for (int k = 0; k < 41; k++) acc[k] = 0.f;
  const int tpr = H >> 5;
  const int nT = tpr * tpr;
  const int tid = threadIdx.x;
  const int tx4 = tid & 7, ty = tid >> 3;
  for (int ti = blockIdx.x; ti < nT; ti += gridDim.x) {
    __syncthreads();
    int by = (ti / tpr) << 5, bx = (ti % tpr) << 5;
    for (int ii = tid; ii < 1600; ii += 256) {
      int r = ii / 40, c = ii - r * 40;
      int gy = (by + r - 4) & (H - 1), gx = (bx + c - 4) & (H - 1);
      float2 v = in[(size_t)gy * H + gx];
      tile[r][c] = mode ? sqrtf(v.x * v.x + v.y * v.y) : v.x;
    }
    __syncthreads();
    float r9[8];
    #pragma unroll
    for (int j = 0; j < 8; j++) r9[j] = tile[ty + 4][4 * tx4 + 4 + j];
    float cen[4] = { r9[0], r9[1], r9[2], r9[3] };
    #pragma unroll
    for (int dx = 0; dx <= 4; dx++) {
      float s = 0.f;
      #pragma unroll
      for (int c = 0; c < 4; c++) s += cen[c] * r9[c + dx];
      acc[dx] += s;
    }
    #pragma unroll
    for (int dy = 1; dy <= 4; dy++) {
      float r[12];
      #pragma unroll
      for (int j = 0; j < 12; j++) r[j] = tile[ty + 4 + dy][4 * tx4 + j];
      #pragma unroll
      for (int dx = -4; dx <= 4; dx++) {
        float s = 0.f;
        #pragma unroll
        for (int c = 0; c < 4; c++) s += cen[c] * r[c + dx + 4];
        acc[5 + (dy - 1) * 9 + dx + 4] += s;
      }
    }
  }
  int wave = tid >> 6, lane = tid & 63;
  #pragma unroll
  for (int k = 0; k < 41; k++) {
    float x = acc[k];
    #pragma unroll
    for (int o = 32; o; o >>= 1) x += __shfl_down(x, o, 64);
    if (lane == 0) fred[wave * 41 + k] = x;
  }
  __syncthreads();
  for (int k = tid; k < 41; k += 256)
    atomicAdd(&g[k], (double)(fred[k] + fred[41 + k] + fred[82 + k] + fred[123 + k]));
}

// raw Grams of 4 band planes (strided partitions)
__global__ __launch_bounds__(256, 4) void k_gram4(const float2* __restrict__ b0, const float2* __restrict__ b1,
                                                  const float2* __restrict__ b2, const float2* __restrict__ b3,
                                                  int n, double* stg, int c0o, int cro) {
  __shared__ float red[128];
  double* base = stg + (size_t)(blockIdx.x & (NP - 1)) * PSZ;
  float acc[32];
  #pragma unroll
  for (int k = 0; k < 32; k++) acc[k] = 0.f;
  for (int i = blockIdx.x * 256 + threadIdx.x; i < n; i += gridDim.x * 256) {
    float2 v0 = b0[i], v1 = b1[i], v2 = b2[i], v3 = b3[i];
    float a[4] = { sqrtf(v0.x * v0.x + v0.y * v0.y), sqrtf(v1.x * v1.x + v1.y * v1.y),
                   sqrtf(v2.x * v2.x + v2.y * v2.y), sqrtf(v3.x * v3.x + v3.y * v3.y) };
    float r[4] = { v0.x, v1.x, v2.x, v3.x };
    #pragma unroll
    for (int ii = 0; ii < 4; ii++)
      #pragma unroll
      for (int jj = 0; jj < 4; jj++) { acc[ii * 4 + jj] += a[ii] * a[jj]; acc[16 + ii * 4 + jj] += r[ii] * r[jj]; }
  }
  blk_reduce<32>(acc, red);
  int tid = threadIdx.x;
  if (tid < 16) atomicAdd(&base[c0o + tid], (double)red[tid]);
  else if (tid < 32) atomicAdd(&base[cro + tid - 16], (double)red[tid]);
}

__global__ __launch_bounds__(256, 4) void k_dots_rpar5(const float2* __restrict__ P,
                                                       const float2* __restrict__ b0, const float2* __restrict__ b1,
                                                       const float2* __restrict__ b2, const float2* __restrict__ b3,
                                                       double* stg) {
  __shared__ float red[80];
  double* base = stg + (size_t)(blockIdx.x & (NP - 1)) * PSZ;
  float acc[20];
  #pragma unroll
  for (int k = 0; k < 20; k++) acc[k] = 0.f;
  for (int i = blockIdx.x * 256 + threadIdx.x; i < 16384; i += gridDim.x * 256) {
    int y = i >> 7, x = i & 127;
    float tt[5];
    tt[0] = P[i].x;
    tt[1] = P[(y << 7) | ((x - 1) & 127)].x;
    tt[2] = P[(y << 7) | ((x + 1) & 127)].x;
    tt[3] = P[(((y - 1) & 127) << 7) | x].x;
    tt[4] = P[(((y + 1) & 127) << 7) | x].x;
    float r[4] = { b0[i].x, b1[i].x, b2[i].x, b3[i].x };
    #pragma unroll
    for (int a = 0; a < 4; a++)
      #pragma unroll
      for (int c = 0; c < 5; c++) acc[a * 5 + c] += r[a] * tt[c];
  }
  blk_reduce<20>(acc, red);
  int tid = threadIdx.x;
  if (tid < 20) atomicAdd(&base[PP_CRX + 96 + (tid / 5) * 8 + (tid % 5)], (double)red[tid]);
}
__global__ __launch_bounds__(256, 4) void k_gram5(const float2* __restrict__ P, double* stg) {
  __shared__ float red[100];
  double* base = stg + (size_t)(blockIdx.x & (NP - 1)) * PSZ;
  float acc[25];
  #pragma unroll
  for (int k = 0; k < 25; k++) acc[k] = 0.f;
  for (int i = blockIdx.x * 256 + threadIdx.x; i < 16384; i += gridDim.x * 256) {
    int y = i >> 7, x = i & 127;
    float tt[5];
    tt[0] = P[i].x;
    tt[1] = P[(y << 7) | ((x - 1) & 127)].x;
    tt[2] = P[(y << 7) | ((x + 1) & 127)].x;
    tt[3] = P[(((y - 1) & 127) << 7) | x].x;
    tt[4] = P[(((y + 1) & 127) << 7) | x].x;
    #pragma unroll
    for (int a = 0; a < 5; a++)
      #pragma unroll
      for (int c = 0; c < 5; c++) acc[a * 5 + c] += tt[a] * tt[c];
  }
  blk_reduce<25>(acc, red);
  int tid = threadIdx.x;
  if (tid < 25) atomicAdd(&base[PP_CR5 + tid], (double)red[tid]);
}

// ================= finalize (sums strided partitions) =================
__global__ __launch_bounds__(256) void k_finalize(const double* __restrict__ stg, const unsigned* __restrict__ stgu,
                                                  float* __restrict__ out) {
  int t = blockIdx.x * 256 + threadIdx.x;
  if (t >= 2456) return;
  const double N = 1048576.0;
  auto sumP = [&](int off) -> double {
    double s = 0.0;
    #pragma unroll
    for (int k = 0; k < NP; k++) s += stg[(size_t)k * PSZ + off];
    return s;
  };
  auto sumA = [&](int pi, int so) -> double {
    double s = 0.0;
    #pragma unroll
    for (int pp = 0; pp < ACPART; pp++) s += stg[SG_ACP + (size_t)(pp * 21 + pi) * ACSTRIDE + so];
    return s;
  };
  double m1 = sumP(PP_PIX) / N, m2 = sumP(PP_PIX + 1) / N;
  double vp = m2 - m1 * m1;
  if (t < 6) {
    double m3 = sumP(PP_PIX + 2) / N, m4 = sumP(PP_PIX + 3) / N;
    double cm3 = m3 - 3.0 * m1 * m2 + 2.0 * m1 * m1 * m1;
    double cm4 = m4 - 4.0 * m1 * m3 + 6.0 * m1 * m1 * m2 - 3.0 * m1 * m1 * m1 * m1;
    double r;
    if (t == 0) r = m1;
    else if (t == 1) r = vp * (N / (N - 1.0));
    else if (t == 2) r = cm3 / (vp * sqrt(vp));
    else if (t == 3) r = cm4 / (vp * vp);
    else if (t == 4) {
      unsigned k = 0xFFFFFFFFu;
      for (int i = 0; i < NP; i++) k = min(k, stgu[i * 32 + 1]);
      r = (double)funkey(k);
    } else {
      unsigned k = 0u;
      for (int i = 0; i < NP; i++) k = max(k, stgu[i * 32]);
      r = (double)funkey(k);
    }
    out[t] = (float)r;
  } else if (t < 24) {
    int i = t - 6;
    double csz;
    if (i == 0) csz = 1048576.0;
    else if (i < 17) { int s = (i - 1) >> 2; double h = (double)(1024 >> s); csz = h * h; }
    else csz = 4096.0;
    out[t] = (float)(sumP(PP_MAG + i) / csz);
  } else if (t < 1320) {
    int e = t - 24;
    int b = e & 3, s = (e >> 2) & 3, o = e >> 4;
    double h = (double)(1024 >> s); double csz = h * h;
    double m = sumP(PP_MAG + 1 + 4 * s + b) / csz;
    out[t] = (float)(sumA(s * 4 + b, sidx(o)) / csz - m * m);
  } else if (t < 1330) {
    int kurt = (t >= 1325);
    int s = t - (kurt ? 1325 : 1320);
    double h = (double)(1024 >> s); double csz = h * h;
    double vari = sumP(PP_IMM + s * 3) / csz;
    double var0 = vp * (N / (N - 1.0));
    double v = vari > 1e-12 ? vari : 1e-12;
    double r;
    if (vari / var0 > 1e-6)
      r = kurt ? (sumP(PP_IMM + s * 3 + 2) / csz) / (v * v)
               : (sumP(PP_IMM + s * 3 + 1) / csz) / (v * sqrt(v));
    else
      r = kurt ? 3.0 : 0.0;
    out[t] = (float)r;
  } else if (t < 1735) {
    int e = t - 1330;
    int s = e % 5, o = e / 5;
    double h = (double)(1024 >> s);
    out[t] = (float)(sumA(16 + s, sidx(o)) / (h * h));
  } else if (t < 1815) {
    int e = t - 1735;
    int s = e % 5, o = e / 5;
    if (s < 4) {
      double h = (double)(1024 >> s); double csz = h * h;
      int i = o >> 2, j = o & 3;
      double mi = sumP(PP_MAG + 1 + 4 * s + i) / csz;
      double mj = sumP(PP_MAG + 1 + 4 * s + j) / csz;
      out[t] = (float)(sumP(PP_C0 + s * 16 + o) / csz - mi * mj);
    } else out[t] = 0.0f;
  } else if (t < 1879) {
    int e = t - 1815;
    int s = e & 3, o = e >> 2;
    if (s < 3) {
      double h = (double)(1024 >> s); double csz = h * h;
      int c = o >> 2, b = o & 3;
      double mc = sumP(PP_MAG + 1 + 4 * s + c) / csz;
      double pm = sumP(PP_PMAG + 4 * s + b) / csz;
      out[t] = (float)(sumP(PP_CX + s * 16 + o) / csz - mc * pm);
    } else out[t] = 0.0f;
  } else if (t < 2199) {
    int e = t - 1879;
    int s = e % 5, o = e / 5;
    int i = o >> 3, j = o & 7;
    float r = 0.0f;
    if (s < 4) { if (i < 4 && j < 4) { double h = (double)(1024 >> s); r = (float)(sumP(PP_CR + s * 16 + i * 4 + j) / (h * h)); } }
    else { if (i < 5 && j < 5) r = (float)(sumP(PP_CR5 + i * 5 + j) / 4096.0); }
    out[t] = r;
  } else if (t < 2455) {
    int e = t - 2199;
    int s = e & 3, o = e >> 2;
    int i = o >> 3, j = o & 7;
    float r = 0.0f;
    if (i < 4) {
      if (s < 3) { double h = (double)(1024 >> s); r = (float)(sumP(PP_CRX + s * 32 + i * 8 + j) / (h * h)); }
      else if (j < 5) r = (float)(sumP(PP_CRX + 96 + i * 8 + j) / 16384.0);
    }
    out[t] = r;
  } else {
    out[t] = (float)(sumP(PP_HISQ) / N);
  }
}

// ================= host orchestration =================
static inline int rb(int n) { int b = (n + 255) / 256; return b > 256 ? 256 : b; }

struct Bufs {
  const float* img;
  float2* L[5];
  float2* Wg;
  double* stg; unsigned* stgu;
  float* out;
  char* w1;   // 40 MiB, 5 x 8MiB slots
  char* w2;   // 32 MiB, 4 x 8MiB slots
  char* l0raw;
};

template<int N>
static void scale_phase(const Bufs& B, int s, hipStream_t st) {
  constexpr int RPB = FftConst<N>::RPB;
  constexpr size_t PB = (size_t)N * N * 8;
  const int np = (N == 128) ? 6 : 5;
  // --- passA: {im, B0..3 [, Plo]} ---
  { PAp a{}; a.twg = B.Wg;
    a.in[0] = B.L[s]; a.mode[0] = MA_IM; a.aux[0] = 0;
    for (int b = 0; b < 4; b++) { a.in[1 + b] = B.L[s]; a.mode[1 + b] = MA_BAND; a.aux[1 + b] = b; }
    if (np == 6) { a.in[5] = B.L[4]; a.mode[5] = MA_EMBED_LO; a.aux[5] = 0; }
    for (int p = 0; p < np; p++) a.out[p] = (float2*)(B.w1 + p * PB);
    k_passA<N, true><<<dim3(N / RPB, np), 256, 0, st>>>(a); }
  // --- transpose ---
  float2* D[6];
  { TPp t{};
    for (int p = 0; p < np; p++) {
      D[p] = (N <= 512 || p < 4) ? (float2*)(B.w2 + p * PB) : (float2*)B.l0raw;
      t.src[p] = (const float2*)(B.w1 + p * PB); t.dst[p] = D[p];
    }
    k_transpose<<<dim3(N / 32, N / 32, np), 256, 0, st>>>(t, N); }
  // --- passB: spatial + fused stats ---
  { PBp bb{}; bb.twg = B.Wg; bb.stg = B.stg;
    for (int p = 0; p < np; p++) { bb.in[p] = D[p]; bb.out[p] = (float2*)(B.w1 + p * PB); }
    bb.wmode[0] = WB_WRITE_IM; bb.redo[0] = PP_IMM + s * 3;
    for (int b = 0; b < 4; b++) { bb.wmode[1 + b] = WB_WRITE_MAG; bb.redo[1 + b] = PP_MAG + 1 + 4 * s + b; }
    if (np == 6) bb.wmode[5] = WB_WRITE;
    k_passB<N, true><<<dim3(N / RPB, np), 256, 0, st>>>(bb); }
  // --- autocorr (im + 4 bands), strided partitioned symmetric raw sums ---
  { ACp c{};
    c.in[0] = (const float2*)(B.w1); c.pi[0] = 16 + s; c.mode[0] = 0;
    for (int b = 0; b < 4; b++) { c.in[1 + b] = (const float2*)(B.w1 + (1 + b) * PB); c.pi[1 + b] = s * 4 + b; c.mode[1 + b] = 1; }
    int nT = (N / 32) * (N / 32);
    k_autocorr<<<dim3(nT > 256 ? 256 : nT, 5), 256, 0, st>>>(c, N, B.stg + SG_ACP); }
  // --- raw gram ---
  k_gram4<<<rb(N * N), 256, 0, st>>>((const float2*)(B.w1 + PB), (const float2*)(B.w1 + 2 * PB),
                                     (const float2*)(B.w1 + 3 * PB), (const float2*)(B.w1 + 4 * PB),
                                     N * N, B.stg, PP_C0 + s * 16, PP_CR + s * 16);
  if (s < 3) {
    // --- parents: one 4-plane passA, then 2x (transpose + pdots passB) ---
    { PAp a{}; a.twg = B.Wg;
      for (int b = 0; b < 4; b++) { a.in[b] = B.L[s + 1]; a.mode[b] = MA_EMBED_BAND; a.aux[b] = b; a.out[b] = (float2*)(B.w2 + b * PB); }
      k_passA<N, true><<<dim3(N / RPB, 4), 256, 0, st>>>(a); }
    char* td0; char* td1;
    if (N == 1024) { td0 = B.l0raw; td1 = B.w1; }
    else { td0 = B.w2 + 4 * PB; td1 = B.w2 + 5 * PB; }
    for (int pr = 0; pr < 2; pr++) {
      { TPp t{};
        t.src[0] = (const float2*)(B.w2 + (2 * pr) * PB); t.dst[0] = (float2*)td0;
        t.src[1] = (const float2*)(B.w2 + (2 * pr + 1) * PB); t.dst[1] = (float2*)td1;
        k_transpose<<<dim3(N / 32, N / 32, 2), 256, 0, st>>>(t, N); }
      { PBp bb{}; bb.twg = B.Wg; bb.stg = B.stg;
        bb.in[0] = (const float2*)td0; bb.in[1] = (const float2*)td1;
        for (int k = 0; k < 2; k++) { int b = pr * 2 + k; bb.wmode[k] = WB_PDOTS; bb.aux[k] = b; bb.redo[k] = PP_PMAG + 4 * s + b; }
        for (int cc = 0; cc < 4; cc++) bb.Bp[cc] = (const float2*)(B.w1 + (1 + cc) * PB);
        bb.cxo = PP_CX + s * 16; bb.crxo = PP_CRX + s * 32;
        k_passB<N, true><<<dim3(N / RPB, 2), 256, 0, st>>>(bb); }
    }
  } else {
    k_dots_rpar5<<<64, 256, 0, st>>>((const float2*)(B.w1 + 5 * PB),
                                     (const float2*)(B.w1 + PB), (const float2*)(B.w1 + 2 * PB),
                                     (const float2*)(B.w1 + 3 * PB), (const float2*)(B.w1 + 4 * PB),
                                     B.stg);
    k_gram5<<<64, 256, 0, st>>>((const float2*)(B.w1 + 5 * PB), B.stg);
  }
}

extern "C" void kernel_launch(void* const* d_in, const int* in_sizes, int n_in,
                              void* d_out, int out_size, void* d_ws, size_t ws_size,
                              hipStream_t stream) {
  (void)in_sizes; (void)n_in; (void)out_size;
  if (ws_size < 87031808ull) return;   // 83 MiB
  char* w = (char*)d_ws;
  Bufs B;
  B.img = (const float*)d_in[0];
  B.out = (float*)d_out;
  B.L[0] = (float2*)(w + 0ull);
  B.L[1] = (float2*)(w + 8388608ull);
  B.L[2] = (float2*)(w + 10485760ull);
  B.L[3] = (float2*)(w + 11010048ull);
  B.L[4] = (float2*)(w + 11141120ull);
  B.Wg   = (float2*)(w + 11173888ull);
  B.stg  = (double*)(w + 11177984ull);
  B.stgu = (unsigned*)(B.stg + NSTG);
  B.w1   = w + 11534336ull;            // 40 MiB
  B.w2   = w + 53477376ull;            // 32 MiB
  B.l0raw = w;
  hipStream_t st = stream;
  double* stg = B.stg;
  constexpr size_t PB8 = 8388608ull;

  k_init<<<(NSTG + 255) / 256, 256, 0, st>>>(stg, B.stgu, B.Wg);

  // forward fft2 with fused pixel raw moments
  k_fwdA<<<1024, 256, 0, st>>>(B.img, (float2*)(B.w1), B.Wg, stg, B.stgu);
  { TPp t{}; t.src[0] = (const float2*)(B.w1); t.dst[0] = (float2*)(B.w2);
    k_transpose<<<dim3(32, 32, 1), 256, 0, st>>>(t, 1024); }
  { PBp bb{}; bb.twg = B.Wg; bb.stg = stg; bb.in[0] = (const float2*)(B.w2); bb.wmode[0] = WB_FWD_MASK;
    bb.out[0] = (float2*)(B.w1 + PB8); bb.out2 = B.L[0];
    k_passB<1024, false><<<dim3(1024, 1), 256, 0, st>>>(bb); }

  // hi residual: ifft2 of hi-spec, reduce-only (sum|re|, re^2)
  { PAp a{}; a.twg = B.Wg; a.in[0] = (const float2*)(B.w1 + PB8); a.mode[0] = MA_C2; a.aux[0] = 0;
    a.out[0] = (float2*)(B.w1);
    k_passA<1024, true><<<dim3(1024, 1), 256, 0, st>>>(a); }
  { TPp t{}; t.src[0] = (const float2*)(B.w1); t.dst[0] = (float2*)(B.w2);
    k_transpose<<<dim3(32, 32, 1), 256, 0, st>>>(t, 1024); }
  { PBp bb{}; bb.twg = B.Wg; bb.stg = stg; bb.in[0] = (const float2*)(B.w2); bb.wmode[0] = WB_RED_HI;
    bb.redo[0] = PP_MAG; bb.red2o = PP_HISQ;
    k_passB<1024, true><<<dim3(1024, 1), 256, 0, st>>>(bb); }

  // lowpass chain, single dispatch
  k_ldown<<<1360, 256, 0, st>>>(B.L[0], B.L[1], B.L[2], B.L[3], B.L[4]);

  // size-64 batch: {lo-resid (plain ifft of L4), imF4 = L4*lo0}
  {
    constexpr size_t PB = 64ull * 64ull * 8ull;
    constexpr int RPB = FftConst<64>::RPB;
    { PAp a{}; a.twg = B.Wg;
      a.in[0] = B.L[4]; a.mode[0] = MA_C2; a.aux[0] = 0; a.out[0] = (float2*)(B.w1);
      a.in[1] = B.L[4]; a.mode[1] = MA_IMF4; a.aux[1] = 0; a.out[1] = (float2*)(B.w1 + PB);
      k_passA<64, true><<<dim3(64 / RPB, 2), 256, 0, st>>>(a); }
    { TPp t{};
      t.src[0] = (const float2*)(B.w1); t.dst[0] = (float2*)(B.w2);
      t.src[1] = (const float2*)(B.w1 + PB); t.dst[1] = (float2*)(B.w2 + PB);
      k_transpose<<<dim3(2, 2, 2), 256, 0, st>>>(t, 64); }
    { PBp bb{}; bb.twg = B.Wg; bb.stg = stg;
      bb.in[0] = (const float2*)(B.w2); bb.wmode[0] = WB_RED_ABSRE; bb.redo[0] = PP_MAG + 17;
      bb.in[1] = (const float2*)(B.w2 + PB); bb.wmode[1] = WB_WRITE_IM; bb.redo[1] = PP_IMM + 12;
      bb.out[1] = (float2*)(B.w1 + PB);
      k_passB<64, true><<<dim3(64 / RPB, 2), 256, 0, st>>>(bb); }
    { ACp c{}; c.in[0] = (const float2*)(B.w1 + PB); c.pi[0] = 20; c.mode[0] = 0;
      k_autocorr<<<dim3(4, 1), 256, 0, st>>>(c, 64, stg + SG_ACP); }
  }

  // per-scale batches
  scale_phase<128>(B, 3, st);
  scale_phase<256>(B, 2, st);
  scale_phase<512>(B, 1, st);
  scale_phase<1024>(B, 0, st);

  k_finalize<<<10, 256, 0, st>>>(stg, B.stgu, B.out);
}